// Round 3
// baseline (872.762 us; speedup 1.0000x reference)
//
#include <hip/hip_runtime.h>
#include <math.h>

#define NW 3
#define ND 16
#define NSZ 384
#define NHALF 192
#define NPIX 147456    // 384*384
#define QPIX 36864     // 192*192
#define MS2 1024
#define NG 194
#define EPSV 0.001f

typedef float2 cplx;

__device__ __forceinline__ cplx cmul_(cplx a, cplx b){
  return make_float2(a.x*b.x - a.y*b.y, a.x*b.y + a.y*b.x);
}

// load element i of a buffer that is f64 (flag=1) or f32 (flag=0)
__device__ __forceinline__ double ld64(const void* p, long i, int f){
  return f ? ((const double*)p)[i] : (double)((const float*)p)[i];
}

// ---------------- dtype detect: rho_grid bytes 8..15 as double --------------
// f64 storage: rho_grid[1], |v| in [20, 1e5]. f32 storage: bit pattern of two
// floats (~211,~352) -> |double| >= 2^60. Threshold 1e9 separates cleanly.
__global__ void k_detect(const void* rg, int* flag){
  double d = ((const double*)rg)[1];
  *flag = (fabs(d) < 1.0e9) ? 1 : 0;
}

// ---------------- twiddle table (built per-block in LDS, fp64 sincos) -------
template<int DIR>
__device__ __forceinline__ void init_tw(float2* tw){
  for (int j = (int)threadIdx.x; j < NSZ; j += (int)blockDim.x){
    double th = (2.0*M_PI/(double)NSZ)*(double)j;
    double s, c; sincos(th, &s, &c);
    tw[j] = make_float2((float)c, (DIR>0) ? (float)(-s) : (float)s);
  }
}

// ---------------- Stockham DIF mixed-radix FFT, N = 384 = 3*2^7 -------------
// 64 threads per transform (u in [0,64)). b0 = input & final output, b1 = scratch.
// Element j lives at b[j*STR]. 8 stages -> result back in b0, natural order.
template<int STR, int DIR>
__device__ __forceinline__ void fft384(float2* b0, float2* b1, int u, const float2* tw){
  const float KH = (DIR>0) ? 0.86602540378443865f : -0.86602540378443865f;
  float2* X = b0; float2* Y = b1;
  // radix-3 stage: n=384, m=128
  #pragma unroll
  for (int i0 = 0; i0 < 128; i0 += 64){
    int p = i0 + u;
    float2 a = X[p*STR], b = X[(p+128)*STR], c = X[(p+256)*STR];
    float2 t1 = make_float2(b.x+c.x, b.y+c.y);
    float2 y0 = make_float2(a.x+t1.x, a.y+t1.y);
    float2 t2 = make_float2(a.x-0.5f*t1.x, a.y-0.5f*t1.y);
    float2 bd = make_float2(b.x-c.x, b.y-c.y);
    float2 t3 = make_float2(KH*bd.y, -KH*bd.x);
    float2 w1 = tw[p], w2 = tw[2*p];
    float2 y1 = make_float2(t2.x+t3.x, t2.y+t3.y);
    float2 y2 = make_float2(t2.x-t3.x, t2.y-t3.y);
    Y[(3*p+0)*STR] = y0;
    Y[(3*p+1)*STR] = cmul_(y1,w1);
    Y[(3*p+2)*STR] = cmul_(y2,w2);
  }
  __syncthreads();
  { float2* T=X; X=Y; Y=T; }
  // 7 radix-2 stages: s = 3<<st; reads i, i+192; tw idx = (i/s)*s
  #pragma unroll
  for (int st = 0; st < 7; st++){
    const int s = 3 << st;
    #pragma unroll
    for (int i0 = 0; i0 < 192; i0 += 64){
      int i = i0 + u;
      int p = i / s;
      float2 a = X[i*STR];
      float2 b = X[(i+192)*STR];
      float2 w = tw[p*s];
      float2 su = make_float2(a.x+b.x, a.y+b.y);
      float2 di = make_float2(a.x-b.x, a.y-b.y);
      int o = i + p*s;
      Y[o*STR]     = su;
      Y[(o+s)*STR] = cmul_(di,w);
    }
    __syncthreads();
    { float2* T=X; X=Y; Y=T; }
  }
}

// ---------------- K1: psf1d (f64 accum), all 48 (w,d) -----------------------
// psf1d[w,d,r] = (sum_m amp*cos(ph)*H)^2 + (sum_m amp*sin(ph)*H)^2
// (2pi/(wl*S))^2 prefactor dropped: cancels in per-(w,d) normalization.
__global__ __launch_bounds__(256) void k_psf1d(const void* __restrict__ h1d,
    const void* __restrict__ amp, const void* __restrict__ pph,
    const void* __restrict__ Hm, const int* __restrict__ flagp,
    double* __restrict__ psf1d){
  int wd = blockIdx.x;            // w*16+d
  int w = wd >> 4;
  int f = *flagp;
  __shared__ double ac[MS2], as_[MS2];
  double wl = (w==0) ? 6.32e-07 : (w==1 ? 5.5e-07 : 4.5e-07);
  double um2 = (wl*1e6)*(wl*1e6);
  double n_idx = 1.5375 + 0.00829045/um2 - 0.000211046/(um2*um2);
  double coef = (2.0*M_PI/wl)*(n_idx-1.0);
  for (int m = (int)threadIdx.x; m < MS2; m += 256){
    double h = ld64(h1d, m, f);
    double a = ld64(amp, (long)wd*MS2 + m, f);
    double p = ld64(pph, (long)wd*MS2 + m, f);
    double s,c; sincos(coef*h + p, &s, &c);
    ac[m] = a*c; as_[m] = a*s;
  }
  __syncthreads();
  for (int r = (int)threadIdx.x; r < NG; r += 256){
    double sr=0.0, si=0.0;
    if (f){
      const double* Hw = (const double*)Hm + (size_t)w*MS2*NG;
      for (int m=0;m<MS2;m++){
        double h = Hw[(size_t)m*NG + r];
        sr += ac[m]*h; si += as_[m]*h;
      }
    } else {
      const float* Hw = (const float*)Hm + (size_t)w*MS2*NG;
      for (int m=0;m<MS2;m++){
        double h = (double)Hw[(size_t)m*NG + r];
        sr += ac[m]*h; si += as_[m]*h;
      }
    }
    psf1d[(size_t)wd*NG + r] = sr*sr + si*si;
  }
}

// ---------------- K2: interp onto quadrant + per-d quadrant sum (1 channel) -
__global__ __launch_bounds__(256) void k_interp(const double* __restrict__ psf1d_c,
    const void* __restrict__ rg, const void* __restrict__ rs,
    int c, const int* __restrict__ flagp,
    float* __restrict__ q, double* __restrict__ sums_c){
  int d   = blockIdx.x / 144, blk = blockIdx.x % 144;
  int pix = blk*256 + (int)threadIdx.x;     // 0..36863
  int f = *flagp;
  const double* v = psf1d_c + (size_t)d*NG;
  long gbase = (long)c*NG;
  double rho = ld64(rs, (long)c*QPIX + pix, f);
  double g0 = ld64(rg, gbase, f);
  double delta = ld64(rg, gbase+1, f) - g0;
  int i = (int)floor((rho-g0)/delta);
  if (i < 0) i = 0; if (i > 192) i = 192;
  double gi  = ld64(rg, gbase+i,   f);
  double gi1 = ld64(rg, gbase+i+1, f);
  if (i > 0  && rho < gi)  { i--; gi1 = gi; gi = ld64(rg, gbase+i, f); }
  else if (i < 192 && rho > gi1){ i++; gi = gi1; gi1 = ld64(rg, gbase+i+1, f); }
  double gl = ld64(rg, gbase+NG-1, f);
  double val;
  if (rho <= g0)      val = v[0];
  else if (rho >= gl) val = v[NG-1];
  else { double t = (rho-gi)/(gi1-gi); val = v[i] + (v[i+1]-v[i])*t; }
  if (val < 0.0) val = 0.0;
  q[(size_t)d*QPIX + pix] = (float)val;
  __shared__ double red[256];
  red[threadIdx.x] = val;
  __syncthreads();
  for (int s=128; s>0; s>>=1){
    if ((int)threadIdx.x < s) red[threadIdx.x] += red[threadIdx.x+s];
    __syncthreads();
  }
  if (threadIdx.x==0) atomicAdd(&sums_c[d], red[0]);
}

// ---------------- row-pass FFT kernels (4 rows/block, 64 lanes/row) ---------
// forward rows of psf: psf_s[y][x] = q[g(y)][g(x)] / (4*sum) / N^2 (ifft scale folded)
__global__ __launch_bounds__(256) void k_rows_psf(const float* __restrict__ q,
    const double* __restrict__ sums_c, float2* __restrict__ out){
  __shared__ float2 buf0[4][NSZ], buf1[4][NSZ];
  __shared__ float2 tw[NSZ];
  init_tw<1>(tw);
  int d = blockIdx.x / 96, grp = blockIdx.x % 96;
  int rl = threadIdx.x >> 6, u = threadIdx.x & 63;
  int y  = grp*4 + rl;
  int gy = (y < NHALF) ? y : (383 - y);
  float sc = (float)(1.0/(4.0*sums_c[d]*147456.0));
  const float* qrow = q + ((size_t)d*QPIX + (size_t)gy*NHALF);
  #pragma unroll
  for (int k=0;k<6;k++){
    int x = u + 64*k;
    int gx = (x < NHALF) ? x : (383 - x);
    buf0[rl][x] = make_float2(qrow[gx]*sc, 0.f);
  }
  __syncthreads();
  fft384<1,1>(&buf0[rl][0], &buf1[rl][0], u, tw);
  float2* orow = out + ((size_t)d*NPIX + (size_t)y*NSZ);
  #pragma unroll
  for (int k=0;k<6;k++) orow[u+64*k] = buf0[rl][u+64*k];
}

// forward rows of packed (layered + i*cumsum_alpha) for one batch b:
// layered=(idx==d), cum=(idx>=d)
__global__ __launch_bounds__(256) void k_rows_LC(const float* __restrict__ depth,
    int b, float2* __restrict__ out){
  __shared__ float2 buf0[4][NSZ], buf1[4][NSZ];
  __shared__ float2 tw[NSZ];
  init_tw<1>(tw);
  int d = blockIdx.x / 96, grp = blockIdx.x % 96;
  int rl = threadIdx.x >> 6, u = threadIdx.x & 63;
  int y  = grp*4 + rl;
  const float* dr = depth + ((size_t)b*NPIX + (size_t)y*NSZ);
  #pragma unroll
  for (int k=0;k<6;k++){
    int x = u + 64*k;
    int idx = (int)floorf(dr[x]*16.0f);
    idx = idx < 0 ? 0 : (idx > 15 ? 15 : idx);
    buf0[rl][x] = make_float2(idx==d ? 1.f : 0.f, idx>=d ? 1.f : 0.f);
  }
  __syncthreads();
  fft384<1,1>(&buf0[rl][0], &buf1[rl][0], u, tw);
  float2* orow = out + ((size_t)d*NPIX + (size_t)y*NSZ);
  #pragma unroll
  for (int k=0;k<6;k++) orow[u+64*k] = buf0[rl][u+64*k];
}

// forward rows of volume for channel c, batch-packed: re = b0, im = b1
__global__ __launch_bounds__(256) void k_rows_V(const float* __restrict__ im,
    const float* __restrict__ depth, int c, float2* __restrict__ out){
  __shared__ float2 buf0[4][NSZ], buf1[4][NSZ];
  __shared__ float2 tw[NSZ];
  init_tw<1>(tw);
  int d = blockIdx.x / 96, grp = blockIdx.x % 96;
  int rl = threadIdx.x >> 6, u = threadIdx.x & 63;
  int y  = grp*4 + rl;
  const float* i0 = im + (((size_t)0*3 + c)*NPIX + (size_t)y*NSZ);
  const float* i1 = im + (((size_t)1*3 + c)*NPIX + (size_t)y*NSZ);
  const float* d0 = depth + (size_t)y*NSZ;
  const float* d1 = depth + (size_t)NPIX + (size_t)y*NSZ;
  #pragma unroll
  for (int k=0;k<6;k++){
    int x = u + 64*k;
    int ia = (int)floorf(d0[x]*16.0f); ia = ia<0?0:(ia>15?15:ia);
    int ib = (int)floorf(d1[x]*16.0f); ib = ib<0?0:(ib>15?15:ib);
    buf0[rl][x] = make_float2(ia==d ? i0[x] : 0.f, ib==d ? i1[x] : 0.f);
  }
  __syncthreads();
  fft384<1,1>(&buf0[rl][0], &buf1[rl][0], u, tw);
  float2* orow = out + ((size_t)d*NPIX + (size_t)y*NSZ);
  #pragma unroll
  for (int k=0;k<6;k++) orow[u+64*k] = buf0[rl][u+64*k];
}

// generic in-place row FFT (used for inverse rows)
template<int DIR>
__global__ __launch_bounds__(256) void k_fft_rows(float2* data){
  __shared__ float2 buf0[4][NSZ], buf1[4][NSZ];
  __shared__ float2 tw[NSZ];
  init_tw<DIR>(tw);
  int rl = threadIdx.x >> 6, u = threadIdx.x & 63;
  float2* row = data + ((size_t)blockIdx.x*4 + rl)*NSZ;
  #pragma unroll
  for (int k=0;k<6;k++) buf0[rl][u+64*k] = row[u+64*k];
  __syncthreads();
  fft384<1,DIR>(&buf0[rl][0], &buf1[rl][0], u, tw);
  #pragma unroll
  for (int k=0;k<6;k++) row[u+64*k] = buf0[rl][u+64*k];
}

// ---------------- column-pass FFT kernels (8 cols/block, 512 threads) -------
template<int DIR>
__global__ __launch_bounds__(512) void k_fft_cols(float2* data){
  __shared__ float2 buf0[NSZ*9], buf1[NSZ*9];
  __shared__ float2 tw[NSZ];
  init_tw<DIR>(tw);
  int img = blockIdx.x / 48, cg = blockIdx.x % 48;
  float2* base = data + (size_t)img*NPIX + (size_t)cg*8;
  int j = threadIdx.x & 7, r0 = threadIdx.x >> 3;
  #pragma unroll
  for (int k=0;k<6;k++){
    int r = r0 + 64*k;
    buf0[r*9 + j] = base[(size_t)r*NSZ + j];
  }
  __syncthreads();
  int cc = threadIdx.x >> 6, u = threadIdx.x & 63;
  fft384<9,DIR>(&buf0[cc], &buf1[cc], u, tw);
  #pragma unroll
  for (int k=0;k<6;k++){
    int r = r0 + 64*k;
    base[(size_t)r*NSZ + j] = buf0[r*9 + j];
  }
}

// inverse column FFT with spectral multiply fused on load:
// dst[img] = colFFT^-1( src[img] * F[img] ),  img in [0,16)
__global__ __launch_bounds__(512) void k_fft_cols_mul_inv(const float2* __restrict__ src,
    const float2* __restrict__ fm, float2* __restrict__ dst){
  __shared__ float2 buf0[NSZ*9], buf1[NSZ*9];
  __shared__ float2 tw[NSZ];
  init_tw<-1>(tw);
  int img = blockIdx.x / 48, cg = blockIdx.x % 48;
  size_t boff = (size_t)img*NPIX + (size_t)cg*8;
  const float2* fbase = fm + boff;
  int j = threadIdx.x & 7, r0 = threadIdx.x >> 3;
  #pragma unroll
  for (int k=0;k<6;k++){
    int r = r0 + 64*k;
    buf0[r*9 + j] = cmul_(src[boff + (size_t)r*NSZ + j], fbase[(size_t)r*NSZ + j]);
  }
  __syncthreads();
  int cc = threadIdx.x >> 6, u = threadIdx.x & 63;
  fft384<9,-1>(&buf0[cc], &buf1[cc], u, tw);
  #pragma unroll
  for (int k=0;k<6;k++){
    int r = r0 + 64*k;
    dst[boff + (size_t)r*NSZ + j] = buf0[r*9 + j];
  }
}

// ---------------- final compositing (one channel, one batch) ----------------
// LC[d] spatial complex: re = blur(layered), im = blur(cumsum)
// V[d]  spatial complex: re = blur(vol b0), im = blur(vol b1)
__global__ __launch_bounds__(256) void k_combine(const float2* __restrict__ LC,
    const float2* __restrict__ V, float* __restrict__ out, int c, int b){
  int pix = blockIdx.x*256 + (int)threadIdx.x;   // < 147456
  float over = 1.f, acc = 0.f;
  for (int d=0; d<ND; d++){
    float2 ac = LC[(size_t)d*NPIX + pix];
    float2 vv = V[(size_t)d*NPIX + pix];
    float Vb = (b==0) ? vv.x : vv.y;
    float ic = 1.f/(ac.y + EPSV);
    acc  += over * (Vb * ic);
    over *= (1.f - ac.x * ic);
  }
  out[((size_t)b*3 + c)*NPIX + pix] = acc;
}

extern "C" void kernel_launch(void* const* d_in, const int* in_sizes, int n_in,
                              void* d_out, int out_size, void* d_ws, size_t ws_size,
                              hipStream_t stream){
  const float* img   = (const float*)d_in[0];   // (2,3,384,384) f32
  const float* depth = (const float*)d_in[1];   // (2,1,384,384) f32
  const void*  h1d   = d_in[2];                 // (1024,) f64 or f32
  const void*  amp   = d_in[3];                 // (3,16,1024)
  const void*  pph   = d_in[4];                 // (3,16,1024)
  const void*  Hm    = d_in[5];                 // (3,1024,194)
  const void*  rg    = d_in[6];                 // (3,194)
  const void*  rs    = d_in[7];                 // (3,192,192)
  float* out = (float*)d_out;
  (void)in_sizes; (void)n_in; (void)out_size;

  char* ws = (char*)d_ws;
  size_t off = 0;
  auto take = [&](size_t b)->char*{ char* p = ws + off; off += (b + 255) & ~(size_t)255; return p; };
  int*    flag  = (int*)   take(256);
  double* psf1d = (double*)take((size_t)48*NG*8);      //   74.5 KB
  double* sums  = (double*)take((size_t)48*8);         //    0.4 KB
  float*  q     = (float*) take((size_t)16*QPIX*4);    //    2.4 MB (per channel)
  float2* Fc    = (float2*)take((size_t)16*NPIX*8);    //   18.9 MB (per channel)
  float2* Vc    = (float2*)take((size_t)16*NPIX*8);    //   18.9 MB (per channel)
  float2* LCb   = (float2*)take((size_t)16*NPIX*8);    //   18.9 MB (per channel+batch)
  if (off > ws_size) return;  // workspace too small -> clean absmax failure, not a fault

  k_detect<<<1, 1, 0, stream>>>(rg, flag);
  hipMemsetAsync(sums, 0, 48*8, stream);
  k_psf1d<<<48, 256, 0, stream>>>(h1d, amp, pph, Hm, flag, psf1d);

  for (int c=0; c<3; c++){
    // PSF spectrum for this channel (16 depths), normalization + 1/N^2 folded
    k_interp<<<16*144, 256, 0, stream>>>(psf1d + (size_t)c*16*NG, rg, rs, c, flag,
                                         q, sums + (size_t)c*16);
    k_rows_psf<<<16*96, 256, 0, stream>>>(q, sums + (size_t)c*16, Fc);
    k_fft_cols<1><<<16*48, 512, 0, stream>>>(Fc);
    // volume (batch-packed): fwd rows+cols, fused mul+inv cols, inv rows
    k_rows_V<<<16*96, 256, 0, stream>>>(img, depth, c, Vc);
    k_fft_cols<1><<<16*48, 512, 0, stream>>>(Vc);
    k_fft_cols_mul_inv<<<16*48, 512, 0, stream>>>(Vc, Fc, Vc);
    k_fft_rows<-1><<<16*96, 256, 0, stream>>>(Vc);
    for (int b=0; b<2; b++){
      // layered + i*cumsum for this batch: fwd, fused mul+inv, inv rows
      k_rows_LC<<<16*96, 256, 0, stream>>>(depth, b, LCb);
      k_fft_cols<1><<<16*48, 512, 0, stream>>>(LCb);
      k_fft_cols_mul_inv<<<16*48, 512, 0, stream>>>(LCb, Fc, LCb);
      k_fft_rows<-1><<<16*96, 256, 0, stream>>>(LCb);
      k_combine<<<576, 256, 0, stream>>>(LCb, Vc, out, c, b);
    }
  }
}

// Round 4
// 713.609 us; speedup vs baseline: 1.2230x; 1.2230x over previous
//
#include <hip/hip_runtime.h>
#include <math.h>

#define NW 3
#define ND 16
#define NSZ 384
#define NHALF 192
#define NPIX 147456    // 384*384
#define QPIX 36864     // 192*192
#define MS2 1024
#define NG 194
#define EPSV 0.001f

typedef float2 cplx;

__device__ __forceinline__ cplx cmul_(cplx a, cplx b){
  return make_float2(a.x*b.x - a.y*b.y, a.x*b.y + a.y*b.x);
}

// load element i of a buffer that is f64 (flag=1) or f32 (flag=0)
__device__ __forceinline__ double ld64(const void* p, long i, int f){
  return f ? ((const double*)p)[i] : (double)((const float*)p)[i];
}

// ---------------- dtype detect: rho_grid bytes 8..15 as double --------------
// f64 storage: rho_grid[1], |v| ~1e2..1e5. f32 storage: bit pattern of two
// floats -> |double| >= 2^60. Threshold 1e9 separates cleanly.
__global__ void k_detect(const void* rg, int* flag){
  double d = ((const double*)rg)[1];
  *flag = (fabs(d) < 1.0e9) ? 1 : 0;
}

// ---------------- unified twiddle table: tw[j] = e^{-2pi i j/384} ------------
__device__ __forceinline__ void init_tw(float2* tw){
  for (int j = (int)threadIdx.x; j < NSZ; j += (int)blockDim.x){
    double th = (2.0*M_PI/(double)NSZ)*(double)j;
    double s, c; sincos(th, &s, &c);
    tw[j] = make_float2((float)c, (float)(-s));
  }
}
template<int DIR>
__device__ __forceinline__ float2 twget(const float2* tw, int i){
  float2 w = tw[i];
  return (DIR > 0) ? w : make_float2(w.x, -w.y);
}

// ---------------- Stockham DIF mixed-radix FFT, N = 384 = 3*2^7 -------------
// 64 threads per transform (u in [0,64)). b0 = input & final output, b1 = scratch.
// Element j lives at b[j*STR]. 8 stages -> result back in b0, natural order.
template<int STR, int DIR>
__device__ __forceinline__ void fft384(float2* b0, float2* b1, int u, const float2* tw){
  const float KH = (DIR>0) ? 0.86602540378443865f : -0.86602540378443865f;
  float2* X = b0; float2* Y = b1;
  // radix-3 stage: n=384, m=128
  #pragma unroll
  for (int i0 = 0; i0 < 128; i0 += 64){
    int p = i0 + u;
    float2 a = X[p*STR], b = X[(p+128)*STR], c = X[(p+256)*STR];
    float2 t1 = make_float2(b.x+c.x, b.y+c.y);
    float2 y0 = make_float2(a.x+t1.x, a.y+t1.y);
    float2 t2 = make_float2(a.x-0.5f*t1.x, a.y-0.5f*t1.y);
    float2 bd = make_float2(b.x-c.x, b.y-c.y);
    float2 t3 = make_float2(KH*bd.y, -KH*bd.x);
    float2 w1 = twget<DIR>(tw,p), w2 = twget<DIR>(tw,2*p);
    float2 y1 = make_float2(t2.x+t3.x, t2.y+t3.y);
    float2 y2 = make_float2(t2.x-t3.x, t2.y-t3.y);
    Y[(3*p+0)*STR] = y0;
    Y[(3*p+1)*STR] = cmul_(y1,w1);
    Y[(3*p+2)*STR] = cmul_(y2,w2);
  }
  __syncthreads();
  { float2* T=X; X=Y; Y=T; }
  // 7 radix-2 stages: s = 3<<st; reads i, i+192; tw idx = (i/s)*s
  #pragma unroll
  for (int st = 0; st < 7; st++){
    const int s = 3 << st;
    #pragma unroll
    for (int i0 = 0; i0 < 192; i0 += 64){
      int i = i0 + u;
      int p = i / s;
      float2 a = X[i*STR];
      float2 b = X[(i+192)*STR];
      float2 w = twget<DIR>(tw, p*s);
      float2 su = make_float2(a.x+b.x, a.y+b.y);
      float2 di = make_float2(a.x-b.x, a.y-b.y);
      int o = i + p*s;
      Y[o*STR]     = su;
      Y[(o+s)*STR] = cmul_(di,w);
    }
    __syncthreads();
    { float2* T=X; X=Y; Y=T; }
  }
}

// ---------------- K1a: trig precompute: acs/ass[wd][m] = amp*{cos,sin}(phase)
__global__ __launch_bounds__(256) void k_trig(const void* __restrict__ h1d,
    const void* __restrict__ amp, const void* __restrict__ pph,
    const int* __restrict__ flagp, double* __restrict__ acs, double* __restrict__ ass){
  int wd = blockIdx.x;            // w*16+d
  int w = wd >> 4;
  int f = *flagp;
  double wl = (w==0) ? 6.32e-07 : (w==1 ? 5.5e-07 : 4.5e-07);
  double um2 = (wl*1e6)*(wl*1e6);
  double n_idx = 1.5375 + 0.00829045/um2 - 0.000211046/(um2*um2);
  double coef = (2.0*M_PI/wl)*(n_idx-1.0);
  for (int m = (int)threadIdx.x; m < MS2; m += 256){
    double h = ld64(h1d, m, f);
    double a = ld64(amp, (long)wd*MS2 + m, f);
    double p = ld64(pph, (long)wd*MS2 + m, f);
    double s,c; sincos(coef*h + p, &s, &c);
    acs[(size_t)wd*MS2 + m] = a*c;
    ass[(size_t)wd*MS2 + m] = a*s;
  }
}

// ---------------- K1b: dot products: one thread per (wd,r) ------------------
// psf1d[wd,r] = (sum_m acs*H)^2 + (sum_m ass*H)^2  ((2pi/(wl*S))^2 dropped:
// cancels in per-(w,d) normalization.)
__global__ __launch_bounds__(256) void k_dot(const double* __restrict__ acs,
    const double* __restrict__ ass, const void* __restrict__ Hm,
    const int* __restrict__ flagp, double* __restrict__ psf1d){
  int t = blockIdx.x*256 + (int)threadIdx.x;
  if (t >= 48*NG) return;
  int wd = t / NG, r = t - wd*NG;
  int w = wd >> 4;
  int f = *flagp;
  const double* ac = acs + (size_t)wd*MS2;
  const double* as_ = ass + (size_t)wd*MS2;
  double sr0=0,si0=0,sr1=0,si1=0;
  if (f){
    const double* Hw = (const double*)Hm + (size_t)w*MS2*NG + r;
    for (int m=0;m<MS2;m+=2){
      double h0 = Hw[(size_t)m*NG], h1 = Hw[(size_t)(m+1)*NG];
      sr0 += ac[m]*h0;   si0 += as_[m]*h0;
      sr1 += ac[m+1]*h1; si1 += as_[m+1]*h1;
    }
  } else {
    const float* Hw = (const float*)Hm + (size_t)w*MS2*NG + r;
    for (int m=0;m<MS2;m+=2){
      double h0 = (double)Hw[(size_t)m*NG], h1 = (double)Hw[(size_t)(m+1)*NG];
      sr0 += ac[m]*h0;   si0 += as_[m]*h0;
      sr1 += ac[m+1]*h1; si1 += as_[m+1]*h1;
    }
  }
  double sr = sr0+sr1, si = si0+si1;
  psf1d[(size_t)wd*NG + r] = sr*sr + si*si;
}

// ---------------- K2: interp onto quadrant + per-d quadrant sum (1 channel) -
__global__ __launch_bounds__(256) void k_interp(const double* __restrict__ psf1d_c,
    const void* __restrict__ rg, const void* __restrict__ rs,
    int c, const int* __restrict__ flagp,
    float* __restrict__ q, double* __restrict__ sums_c){
  int d   = blockIdx.x / 144, blk = blockIdx.x % 144;
  int pix = blk*256 + (int)threadIdx.x;     // 0..36863
  int f = *flagp;
  const double* v = psf1d_c + (size_t)d*NG;
  long gbase = (long)c*NG;
  double rho = ld64(rs, (long)c*QPIX + pix, f);
  double g0 = ld64(rg, gbase, f);
  double delta = ld64(rg, gbase+1, f) - g0;
  int i = (int)floor((rho-g0)/delta);
  if (i < 0) i = 0; if (i > 192) i = 192;
  double gi  = ld64(rg, gbase+i,   f);
  double gi1 = ld64(rg, gbase+i+1, f);
  if (i > 0  && rho < gi)  { i--; gi1 = gi; gi = ld64(rg, gbase+i, f); }
  else if (i < 192 && rho > gi1){ i++; gi = gi1; gi1 = ld64(rg, gbase+i+1, f); }
  double gl = ld64(rg, gbase+NG-1, f);
  double val;
  if (rho <= g0)      val = v[0];
  else if (rho >= gl) val = v[NG-1];
  else { double t = (rho-gi)/(gi1-gi); val = v[i] + (v[i+1]-v[i])*t; }
  if (val < 0.0) val = 0.0;
  q[(size_t)d*QPIX + pix] = (float)val;
  __shared__ double red[256];
  red[threadIdx.x] = val;
  __syncthreads();
  for (int s=128; s>0; s>>=1){
    if ((int)threadIdx.x < s) red[threadIdx.x] += red[threadIdx.x+s];
    __syncthreads();
  }
  if (threadIdx.x==0) atomicAdd(&sums_c[d], red[0]);
}

// ---------------- row-pass FFT kernels (4 rows/block, 64 lanes/row) ---------
// forward rows of psf: psf_s[y][x] = q[g(y)][g(x)] / (4*sum) / N^2 (ifft scale folded)
__global__ __launch_bounds__(256) void k_rows_psf(const float* __restrict__ q,
    const double* __restrict__ sums_c, float2* __restrict__ out){
  __shared__ float2 buf0[4][NSZ], buf1[4][NSZ];
  __shared__ float2 tw[NSZ];
  init_tw(tw);
  int d = blockIdx.x / 96, grp = blockIdx.x % 96;
  int rl = threadIdx.x >> 6, u = threadIdx.x & 63;
  int y  = grp*4 + rl;
  int gy = (y < NHALF) ? y : (383 - y);
  float sc = (float)(1.0/(4.0*sums_c[d]*147456.0));
  const float* qrow = q + ((size_t)d*QPIX + (size_t)gy*NHALF);
  #pragma unroll
  for (int k=0;k<6;k++){
    int x = u + 64*k;
    int gx = (x < NHALF) ? x : (383 - x);
    buf0[rl][x] = make_float2(qrow[gx]*sc, 0.f);
  }
  __syncthreads();
  fft384<1,1>(&buf0[rl][0], &buf1[rl][0], u, tw);
  float2* orow = out + ((size_t)d*NPIX + (size_t)y*NSZ);
  #pragma unroll
  for (int k=0;k<6;k++) orow[u+64*k] = buf0[rl][u+64*k];
}

// forward rows of packed (layered + i*cumsum_alpha) for one batch b:
// layered=(idx==d), cum=(idx>=d)
__global__ __launch_bounds__(256) void k_rows_LC(const float* __restrict__ depth,
    int b, float2* __restrict__ out){
  __shared__ float2 buf0[4][NSZ], buf1[4][NSZ];
  __shared__ float2 tw[NSZ];
  init_tw(tw);
  int d = blockIdx.x / 96, grp = blockIdx.x % 96;
  int rl = threadIdx.x >> 6, u = threadIdx.x & 63;
  int y  = grp*4 + rl;
  const float* dr = depth + ((size_t)b*NPIX + (size_t)y*NSZ);
  #pragma unroll
  for (int k=0;k<6;k++){
    int x = u + 64*k;
    int idx = (int)floorf(dr[x]*16.0f);
    idx = idx < 0 ? 0 : (idx > 15 ? 15 : idx);
    buf0[rl][x] = make_float2(idx==d ? 1.f : 0.f, idx>=d ? 1.f : 0.f);
  }
  __syncthreads();
  fft384<1,1>(&buf0[rl][0], &buf1[rl][0], u, tw);
  float2* orow = out + ((size_t)d*NPIX + (size_t)y*NSZ);
  #pragma unroll
  for (int k=0;k<6;k++) orow[u+64*k] = buf0[rl][u+64*k];
}

// forward rows of volume for channel c, batch-packed: re = b0, im = b1
__global__ __launch_bounds__(256) void k_rows_V(const float* __restrict__ im,
    const float* __restrict__ depth, int c, float2* __restrict__ out){
  __shared__ float2 buf0[4][NSZ], buf1[4][NSZ];
  __shared__ float2 tw[NSZ];
  init_tw(tw);
  int d = blockIdx.x / 96, grp = blockIdx.x % 96;
  int rl = threadIdx.x >> 6, u = threadIdx.x & 63;
  int y  = grp*4 + rl;
  const float* i0 = im + (((size_t)0*3 + c)*NPIX + (size_t)y*NSZ);
  const float* i1 = im + (((size_t)1*3 + c)*NPIX + (size_t)y*NSZ);
  const float* d0 = depth + (size_t)y*NSZ;
  const float* d1 = depth + (size_t)NPIX + (size_t)y*NSZ;
  #pragma unroll
  for (int k=0;k<6;k++){
    int x = u + 64*k;
    int ia = (int)floorf(d0[x]*16.0f); ia = ia<0?0:(ia>15?15:ia);
    int ib = (int)floorf(d1[x]*16.0f); ib = ib<0?0:(ib>15?15:ib);
    buf0[rl][x] = make_float2(ia==d ? i0[x] : 0.f, ib==d ? i1[x] : 0.f);
  }
  __syncthreads();
  fft384<1,1>(&buf0[rl][0], &buf1[rl][0], u, tw);
  float2* orow = out + ((size_t)d*NPIX + (size_t)y*NSZ);
  #pragma unroll
  for (int k=0;k<6;k++) orow[u+64*k] = buf0[rl][u+64*k];
}

// generic in-place row FFT (used for inverse rows)
template<int DIR>
__global__ __launch_bounds__(256) void k_fft_rows(float2* data){
  __shared__ float2 buf0[4][NSZ], buf1[4][NSZ];
  __shared__ float2 tw[NSZ];
  init_tw(tw);
  int rl = threadIdx.x >> 6, u = threadIdx.x & 63;
  float2* row = data + ((size_t)blockIdx.x*4 + rl)*NSZ;
  #pragma unroll
  for (int k=0;k<6;k++) buf0[rl][u+64*k] = row[u+64*k];
  __syncthreads();
  fft384<1,DIR>(&buf0[rl][0], &buf1[rl][0], u, tw);
  #pragma unroll
  for (int k=0;k<6;k++) row[u+64*k] = buf0[rl][u+64*k];
}

// ---------------- column-pass FFT kernels (8 cols/block, 512 threads) -------
template<int DIR>
__global__ __launch_bounds__(512) void k_fft_cols(float2* data){
  __shared__ float2 buf0[NSZ*9], buf1[NSZ*9];
  __shared__ float2 tw[NSZ];
  init_tw(tw);
  int img = blockIdx.x / 48, cg = blockIdx.x % 48;
  float2* base = data + (size_t)img*NPIX + (size_t)cg*8;
  int j = threadIdx.x & 7, r0 = threadIdx.x >> 3;
  #pragma unroll
  for (int k=0;k<6;k++){
    int r = r0 + 64*k;
    buf0[r*9 + j] = base[(size_t)r*NSZ + j];
  }
  __syncthreads();
  int cc = threadIdx.x >> 6, u = threadIdx.x & 63;
  fft384<9,DIR>(&buf0[cc], &buf1[cc], u, tw);
  #pragma unroll
  for (int k=0;k<6;k++){
    int r = r0 + 64*k;
    base[(size_t)r*NSZ + j] = buf0[r*9 + j];
  }
}

// FUSED: forward col FFT + spectral multiply + inverse col FFT, in place.
// data[img] (row-FFT'd) -> colIFFT( colFFT(data) * F[img] ), img in [0,16)
__global__ __launch_bounds__(512) void k_fused_cols(float2* data,
    const float2* __restrict__ fm){
  __shared__ float2 buf0[NSZ*9], buf1[NSZ*9];
  __shared__ float2 tw[NSZ];
  init_tw(tw);
  int img = blockIdx.x / 48, cg = blockIdx.x % 48;
  size_t boff = (size_t)img*NPIX + (size_t)cg*8;
  int j = threadIdx.x & 7, r0 = threadIdx.x >> 3;
  #pragma unroll
  for (int k=0;k<6;k++){
    int r = r0 + 64*k;
    buf0[r*9 + j] = data[boff + (size_t)r*NSZ + j];
  }
  __syncthreads();
  int cc = threadIdx.x >> 6, u = threadIdx.x & 63;
  fft384<9,1>(&buf0[cc], &buf1[cc], u, tw);
  // spectrum now in buf0 (natural order); element-wise multiply by F
  const float2* fbase = fm + boff;
  #pragma unroll
  for (int k=0;k<6;k++){
    int r = r0 + 64*k;
    buf0[r*9 + j] = cmul_(buf0[r*9 + j], fbase[(size_t)r*NSZ + j]);
  }
  __syncthreads();
  fft384<9,-1>(&buf0[cc], &buf1[cc], u, tw);
  #pragma unroll
  for (int k=0;k<6;k++){
    int r = r0 + 64*k;
    data[boff + (size_t)r*NSZ + j] = buf0[r*9 + j];
  }
}

// inverse column FFT with spectral multiply fused on load (src is 2D spectrum):
// dst[img] = colFFT^-1( src[img] * F[img] ),  img in [0,16)
__global__ __launch_bounds__(512) void k_mulinv_cols(const float2* __restrict__ src,
    const float2* __restrict__ fm, float2* __restrict__ dst){
  __shared__ float2 buf0[NSZ*9], buf1[NSZ*9];
  __shared__ float2 tw[NSZ];
  init_tw(tw);
  int img = blockIdx.x / 48, cg = blockIdx.x % 48;
  size_t boff = (size_t)img*NPIX + (size_t)cg*8;
  const float2* fbase = fm + boff;
  int j = threadIdx.x & 7, r0 = threadIdx.x >> 3;
  #pragma unroll
  for (int k=0;k<6;k++){
    int r = r0 + 64*k;
    buf0[r*9 + j] = cmul_(src[boff + (size_t)r*NSZ + j], fbase[(size_t)r*NSZ + j]);
  }
  __syncthreads();
  int cc = threadIdx.x >> 6, u = threadIdx.x & 63;
  fft384<9,-1>(&buf0[cc], &buf1[cc], u, tw);
  #pragma unroll
  for (int k=0;k<6;k++){
    int r = r0 + 64*k;
    dst[boff + (size_t)r*NSZ + j] = buf0[r*9 + j];
  }
}

// ---------------- final compositing (one channel, one batch) ----------------
// LC[d] spatial complex: re = blur(layered), im = blur(cumsum)
// V[d]  spatial complex: re = blur(vol b0), im = blur(vol b1)
__global__ __launch_bounds__(256) void k_combine(const float2* __restrict__ LC,
    const float2* __restrict__ V, float* __restrict__ out, int c, int b){
  int pix = blockIdx.x*256 + (int)threadIdx.x;   // < 147456
  float over = 1.f, acc = 0.f;
  for (int d=0; d<ND; d++){
    float2 ac = LC[(size_t)d*NPIX + pix];
    float2 vv = V[(size_t)d*NPIX + pix];
    float Vb = (b==0) ? vv.x : vv.y;
    float ic = 1.f/(ac.y + EPSV);
    acc  += over * (Vb * ic);
    over *= (1.f - ac.x * ic);
  }
  out[((size_t)b*3 + c)*NPIX + pix] = acc;
}

extern "C" void kernel_launch(void* const* d_in, const int* in_sizes, int n_in,
                              void* d_out, int out_size, void* d_ws, size_t ws_size,
                              hipStream_t stream){
  const float* img   = (const float*)d_in[0];   // (2,3,384,384) f32
  const float* depth = (const float*)d_in[1];   // (2,1,384,384) f32
  const void*  h1d   = d_in[2];                 // (1024,) f64 or f32
  const void*  amp   = d_in[3];                 // (3,16,1024)
  const void*  pph   = d_in[4];                 // (3,16,1024)
  const void*  Hm    = d_in[5];                 // (3,1024,194)
  const void*  rg    = d_in[6];                 // (3,194)
  const void*  rs    = d_in[7];                 // (3,192,192)
  float* out = (float*)d_out;
  (void)in_sizes; (void)n_in; (void)out_size;

  char* ws = (char*)d_ws;
  size_t off = 0;
  auto take = [&](size_t b)->char*{ char* p = ws + off; off += (b + 255) & ~(size_t)255; return p; };
  int*    flag  = (int*)   take(256);
  double* psf1d = (double*)take((size_t)48*NG*8);      //   74.5 KB
  double* sums  = (double*)take((size_t)48*8);
  double* acs   = (double*)take((size_t)48*MS2*8);     //  384 KB
  double* ass   = (double*)take((size_t)48*MS2*8);     //  384 KB
  float*  q     = (float*) take((size_t)16*QPIX*4);    //  2.4 MB (per channel)
  float2* Fc    = (float2*)take((size_t)16*NPIX*8);    // 18.9 MB (per channel)
  float2* Vc    = (float2*)take((size_t)16*NPIX*8);    // 18.9 MB (per channel)
  float2* L0    = (float2*)take((size_t)16*NPIX*8);    // 18.9 MB
  size_t offB = off;                                   // Path B footprint (~59.5 MB)
  float2* L1    = (float2*)take((size_t)16*NPIX*8);    // 18.9 MB
  float2* S0    = (float2*)take((size_t)16*NPIX*8);    // 18.9 MB  (LC 2D spectrum, b=0)
  float2* S1    = (float2*)take((size_t)16*NPIX*8);    // 18.9 MB  (LC 2D spectrum, b=1)
  size_t offA = off;                                   // Path A footprint (~116 MB)
  if (ws_size < offB) return;  // clean absmax failure, not a fault
  const bool pathA = (ws_size >= offA);

  k_detect<<<1, 1, 0, stream>>>(rg, flag);
  hipMemsetAsync(sums, 0, 48*8, stream);
  k_trig<<<48, 256, 0, stream>>>(h1d, amp, pph, flag, acs, ass);
  k_dot<<<(48*NG + 255)/256, 256, 0, stream>>>(acs, ass, Hm, flag, psf1d);

  if (pathA){
    // precompute LC 2D spectra once per batch
    k_rows_LC<<<16*96, 256, 0, stream>>>(depth, 0, S0);
    k_fft_cols<1><<<16*48, 512, 0, stream>>>(S0);
    k_rows_LC<<<16*96, 256, 0, stream>>>(depth, 1, S1);
    k_fft_cols<1><<<16*48, 512, 0, stream>>>(S1);
  }

  for (int c=0; c<3; c++){
    // PSF spectrum for this channel (16 depths), normalization + 1/N^2 folded
    k_interp<<<16*144, 256, 0, stream>>>(psf1d + (size_t)c*16*NG, rg, rs, c, flag,
                                         q, sums + (size_t)c*16);
    k_rows_psf<<<16*96, 256, 0, stream>>>(q, sums + (size_t)c*16, Fc);
    k_fft_cols<1><<<16*48, 512, 0, stream>>>(Fc);
    // volume (batch-packed): fwd rows, fused (fwd cols + mul + inv cols), inv rows
    k_rows_V<<<16*96, 256, 0, stream>>>(img, depth, c, Vc);
    k_fused_cols<<<16*48, 512, 0, stream>>>(Vc, Fc);
    k_fft_rows<-1><<<16*96, 256, 0, stream>>>(Vc);
    if (pathA){
      k_mulinv_cols<<<16*48, 512, 0, stream>>>(S0, Fc, L0);
      k_fft_rows<-1><<<16*96, 256, 0, stream>>>(L0);
      k_combine<<<576, 256, 0, stream>>>(L0, Vc, out, c, 0);
      k_mulinv_cols<<<16*48, 512, 0, stream>>>(S1, Fc, L1);
      k_fft_rows<-1><<<16*96, 256, 0, stream>>>(L1);
      k_combine<<<576, 256, 0, stream>>>(L1, Vc, out, c, 1);
    } else {
      for (int b=0; b<2; b++){
        k_rows_LC<<<16*96, 256, 0, stream>>>(depth, b, L0);
        k_fused_cols<<<16*48, 512, 0, stream>>>(L0, Fc);
        k_fft_rows<-1><<<16*96, 256, 0, stream>>>(L0);
        k_combine<<<576, 256, 0, stream>>>(L0, Vc, out, c, b);
      }
    }
  }
}

// Round 5
// 706.570 us; speedup vs baseline: 1.2352x; 1.0100x over previous
//
#include <hip/hip_runtime.h>
#include <math.h>

#define NW 3
#define ND 16
#define NSZ 384
#define NHALF 192
#define NPIX 147456    // 384*384
#define QPIX 36864     // 192*192
#define MS2 1024
#define NG 194
#define EPSV 0.001f

typedef float2 cplx;

__device__ __forceinline__ cplx cmul_(cplx a, cplx b){
  return make_float2(a.x*b.x - a.y*b.y, a.x*b.y + a.y*b.x);
}

// load element i of a buffer that is f64 (flag=1) or f32 (flag=0)
__device__ __forceinline__ double ld64(const void* p, long i, int f){
  return f ? ((const double*)p)[i] : (double)((const float*)p)[i];
}

// ---------------- dtype detect: rho_grid bytes 8..15 as double --------------
__global__ void k_detect(const void* rg, int* flag){
  double d = ((const double*)rg)[1];
  *flag = (fabs(d) < 1.0e9) ? 1 : 0;
}

// ---------------- unified twiddle table: tw[j] = e^{-2pi i j/384} ------------
__device__ __forceinline__ void init_tw(float2* tw){
  for (int j = (int)threadIdx.x; j < NSZ; j += (int)blockDim.x){
    double th = (2.0*M_PI/(double)NSZ)*(double)j;
    double s, c; sincos(th, &s, &c);
    tw[j] = make_float2((float)c, (float)(-s));
  }
}
template<int DIR>
__device__ __forceinline__ float2 twget(const float2* tw, int i){
  float2 w = tw[i];
  return (DIR > 0) ? w : make_float2(w.x, -w.y);
}

// ---------------- Stockham DIF mixed-radix FFT, N = 384 = 3*2^7 -------------
// 64 threads per transform (u in [0,64)). Element j at b[j*STR]. Result in b0.
template<int STR, int DIR>
__device__ __forceinline__ void fft384(float2* b0, float2* b1, int u, const float2* tw){
  const float KH = (DIR>0) ? 0.86602540378443865f : -0.86602540378443865f;
  float2* X = b0; float2* Y = b1;
  #pragma unroll
  for (int i0 = 0; i0 < 128; i0 += 64){
    int p = i0 + u;
    float2 a = X[p*STR], b = X[(p+128)*STR], c = X[(p+256)*STR];
    float2 t1 = make_float2(b.x+c.x, b.y+c.y);
    float2 y0 = make_float2(a.x+t1.x, a.y+t1.y);
    float2 t2 = make_float2(a.x-0.5f*t1.x, a.y-0.5f*t1.y);
    float2 bd = make_float2(b.x-c.x, b.y-c.y);
    float2 t3 = make_float2(KH*bd.y, -KH*bd.x);
    float2 w1 = twget<DIR>(tw,p), w2 = twget<DIR>(tw,2*p);
    float2 y1 = make_float2(t2.x+t3.x, t2.y+t3.y);
    float2 y2 = make_float2(t2.x-t3.x, t2.y-t3.y);
    Y[(3*p+0)*STR] = y0;
    Y[(3*p+1)*STR] = cmul_(y1,w1);
    Y[(3*p+2)*STR] = cmul_(y2,w2);
  }
  __syncthreads();
  { float2* T=X; X=Y; Y=T; }
  #pragma unroll
  for (int st = 0; st < 7; st++){
    const int s = 3 << st;
    #pragma unroll
    for (int i0 = 0; i0 < 192; i0 += 64){
      int i = i0 + u;
      int p = i / s;
      float2 a = X[i*STR];
      float2 b = X[(i+192)*STR];
      float2 w = twget<DIR>(tw, p*s);
      float2 su = make_float2(a.x+b.x, a.y+b.y);
      float2 di = make_float2(a.x-b.x, a.y-b.y);
      int o = i + p*s;
      Y[o*STR]     = su;
      Y[(o+s)*STR] = cmul_(di,w);
    }
    __syncthreads();
    { float2* T=X; X=Y; Y=T; }
  }
}

// ---------------- K1a: trig precompute: acs/ass[wd][m] = amp*{cos,sin}(phase)
__global__ __launch_bounds__(256) void k_trig(const void* __restrict__ h1d,
    const void* __restrict__ amp, const void* __restrict__ pph,
    const int* __restrict__ flagp, double* __restrict__ acs, double* __restrict__ ass){
  int wd = blockIdx.x;            // w*16+d
  int w = wd >> 4;
  int f = *flagp;
  double wl = (w==0) ? 6.32e-07 : (w==1 ? 5.5e-07 : 4.5e-07);
  double um2 = (wl*1e6)*(wl*1e6);
  double n_idx = 1.5375 + 0.00829045/um2 - 0.000211046/(um2*um2);
  double coef = (2.0*M_PI/wl)*(n_idx-1.0);
  for (int m = (int)threadIdx.x; m < MS2; m += 256){
    double h = ld64(h1d, m, f);
    double a = ld64(amp, (long)wd*MS2 + m, f);
    double p = ld64(pph, (long)wd*MS2 + m, f);
    double s,c; sincos(coef*h + p, &s, &c);
    acs[(size_t)wd*MS2 + m] = a*c;
    ass[(size_t)wd*MS2 + m] = a*s;
  }
}

// ---------------- K1b: dot partials: block = (wd, 128-m chunk) --------------
__global__ __launch_bounds__(256) void k_dotA(const double* __restrict__ acs,
    const double* __restrict__ ass, const void* __restrict__ Hm,
    const int* __restrict__ flagp, double2* __restrict__ part){
  int wd = blockIdx.x >> 3, ch = blockIdx.x & 7;
  int w = wd >> 4;
  int f = *flagp;
  int m0 = ch << 7;
  __shared__ double sac[128], sas[128];
  int tid = (int)threadIdx.x;
  if (tid < 128){
    sac[tid] = acs[(size_t)wd*MS2 + m0 + tid];
    sas[tid] = ass[(size_t)wd*MS2 + m0 + tid];
  }
  __syncthreads();
  int r = tid;
  if (r < NG){
    double sr=0.0, si=0.0;
    if (f){
      const double* Hw = (const double*)Hm + ((size_t)w*MS2 + m0)*NG + r;
      #pragma unroll 4
      for (int m=0;m<128;m++){
        double h = Hw[(size_t)m*NG];
        sr += sac[m]*h; si += sas[m]*h;
      }
    } else {
      const float* Hw = (const float*)Hm + ((size_t)w*MS2 + m0)*NG + r;
      #pragma unroll 4
      for (int m=0;m<128;m++){
        double h = (double)Hw[(size_t)m*NG];
        sr += sac[m]*h; si += sas[m]*h;
      }
    }
    part[(size_t)blockIdx.x*NG + r] = make_double2(sr, si);
  }
}

// ---------------- K1c: reduce chunks + square -------------------------------
__global__ __launch_bounds__(256) void k_dotB(const double2* __restrict__ part,
    double* __restrict__ psf1d){
  int t = blockIdx.x*256 + (int)threadIdx.x;
  if (t >= 48*NG) return;
  int wd = t / NG, r = t - wd*NG;
  double sr=0.0, si=0.0;
  for (int ch=0; ch<8; ch++){
    double2 pp = part[(size_t)(wd*8+ch)*NG + r];
    sr += pp.x; si += pp.y;
  }
  psf1d[t] = sr*sr + si*si;
}

// ---------------- K2: interp onto quadrant + per-img quadrant sum -----------
// grid nimg*144; wd_off maps local img -> global wd for rg/rs channel.
__global__ __launch_bounds__(256) void k_interp(const double* __restrict__ psf1d_b,
    const void* __restrict__ rg, const void* __restrict__ rs,
    const int* __restrict__ flagp, float* __restrict__ q,
    double* __restrict__ sums_b, int wd_off){
  int wdl = blockIdx.x / 144, blk = blockIdx.x % 144;
  int c = (wdl + wd_off) >> 4;
  int pix = blk*256 + (int)threadIdx.x;     // 0..36863
  int f = *flagp;
  const double* v = psf1d_b + (size_t)wdl*NG;
  long gbase = (long)c*NG;
  double rho = ld64(rs, (long)c*QPIX + pix, f);
  double g0 = ld64(rg, gbase, f);
  double delta = ld64(rg, gbase+1, f) - g0;
  int i = (int)floor((rho-g0)/delta);
  if (i < 0) i = 0; if (i > 192) i = 192;
  double gi  = ld64(rg, gbase+i,   f);
  double gi1 = ld64(rg, gbase+i+1, f);
  if (i > 0  && rho < gi)  { i--; gi1 = gi; gi = ld64(rg, gbase+i, f); }
  else if (i < 192 && rho > gi1){ i++; gi = gi1; gi1 = ld64(rg, gbase+i+1, f); }
  double gl = ld64(rg, gbase+NG-1, f);
  double val;
  if (rho <= g0)      val = v[0];
  else if (rho >= gl) val = v[NG-1];
  else { double t = (rho-gi)/(gi1-gi); val = v[i] + (v[i+1]-v[i])*t; }
  if (val < 0.0) val = 0.0;
  q[(size_t)wdl*QPIX + pix] = (float)val;
  __shared__ double red[256];
  red[threadIdx.x] = val;
  __syncthreads();
  for (int s=128; s>0; s>>=1){
    if ((int)threadIdx.x < s) red[threadIdx.x] += red[threadIdx.x+s];
    __syncthreads();
  }
  if (threadIdx.x==0) atomicAdd(&sums_b[wdl], red[0]);
}

// ---------------- row-pass FFT kernels (4 rows/block, 64 lanes/row) ---------
// forward rows of psf (grid nimg*96): mirror + normalize + 1/N^2 folded
__global__ __launch_bounds__(256) void k_rows_psf(const float* __restrict__ q,
    const double* __restrict__ sums_b, float2* __restrict__ out){
  __shared__ float2 buf0[4][NSZ], buf1[4][NSZ];
  __shared__ float2 tw[NSZ];
  init_tw(tw);
  int d = blockIdx.x / 96, grp = blockIdx.x % 96;
  int rl = threadIdx.x >> 6, u = threadIdx.x & 63;
  int y  = grp*4 + rl;
  int gy = (y < NHALF) ? y : (383 - y);
  float sc = (float)(1.0/(4.0*sums_b[d]*147456.0));
  const float* qrow = q + ((size_t)d*QPIX + (size_t)gy*NHALF);
  #pragma unroll
  for (int k=0;k<6;k++){
    int x = u + 64*k;
    int gx = (x < NHALF) ? x : (383 - x);
    buf0[rl][x] = make_float2(qrow[gx]*sc, 0.f);
  }
  __syncthreads();
  fft384<1,1>(&buf0[rl][0], &buf1[rl][0], u, tw);
  float2* orow = out + ((size_t)d*NPIX + (size_t)y*NSZ);
  #pragma unroll
  for (int k=0;k<6;k++) orow[u+64*k] = buf0[rl][u+64*k];
}

// forward rows of packed (layered + i*cumsum): grid nimg*96, img32 = local+off
__global__ __launch_bounds__(256) void k_rows_LC(const float* __restrict__ depth,
    int off, float2* __restrict__ out){
  __shared__ float2 buf0[4][NSZ], buf1[4][NSZ];
  __shared__ float2 tw[NSZ];
  init_tw(tw);
  int imgl = blockIdx.x / 96, grp = blockIdx.x % 96;
  int img = imgl + off;
  int b = img >> 4, d = img & 15;
  int rl = threadIdx.x >> 6, u = threadIdx.x & 63;
  int y  = grp*4 + rl;
  const float* dr = depth + ((size_t)b*NPIX + (size_t)y*NSZ);
  #pragma unroll
  for (int k=0;k<6;k++){
    int x = u + 64*k;
    int idx = (int)floorf(dr[x]*16.0f);
    idx = idx < 0 ? 0 : (idx > 15 ? 15 : idx);
    buf0[rl][x] = make_float2(idx==d ? 1.f : 0.f, idx>=d ? 1.f : 0.f);
  }
  __syncthreads();
  fft384<1,1>(&buf0[rl][0], &buf1[rl][0], u, tw);
  float2* orow = out + ((size_t)imgl*NPIX + (size_t)y*NSZ);
  #pragma unroll
  for (int k=0;k<6;k++) orow[u+64*k] = buf0[rl][u+64*k];
}

// forward rows of volume, batch-packed re=b0 im=b1: grid nimg*96, img48=local+off
__global__ __launch_bounds__(256) void k_rows_V(const float* __restrict__ im,
    const float* __restrict__ depth, int off, float2* __restrict__ out){
  __shared__ float2 buf0[4][NSZ], buf1[4][NSZ];
  __shared__ float2 tw[NSZ];
  init_tw(tw);
  int imgl = blockIdx.x / 96, grp = blockIdx.x % 96;
  int img = imgl + off;
  int c = img >> 4, d = img & 15;
  int rl = threadIdx.x >> 6, u = threadIdx.x & 63;
  int y  = grp*4 + rl;
  const float* i0 = im + (((size_t)0*3 + c)*NPIX + (size_t)y*NSZ);
  const float* i1 = im + (((size_t)1*3 + c)*NPIX + (size_t)y*NSZ);
  const float* d0 = depth + (size_t)y*NSZ;
  const float* d1 = depth + (size_t)NPIX + (size_t)y*NSZ;
  #pragma unroll
  for (int k=0;k<6;k++){
    int x = u + 64*k;
    int ia = (int)floorf(d0[x]*16.0f); ia = ia<0?0:(ia>15?15:ia);
    int ib = (int)floorf(d1[x]*16.0f); ib = ib<0?0:(ib>15?15:ib);
    buf0[rl][x] = make_float2(ia==d ? i0[x] : 0.f, ib==d ? i1[x] : 0.f);
  }
  __syncthreads();
  fft384<1,1>(&buf0[rl][0], &buf1[rl][0], u, tw);
  float2* orow = out + ((size_t)imgl*NPIX + (size_t)y*NSZ);
  #pragma unroll
  for (int k=0;k<6;k++) orow[u+64*k] = buf0[rl][u+64*k];
}

// generic in-place row FFT (grid nimg*96)
template<int DIR>
__global__ __launch_bounds__(256) void k_fft_rows(float2* data){
  __shared__ float2 buf0[4][NSZ], buf1[4][NSZ];
  __shared__ float2 tw[NSZ];
  init_tw(tw);
  int rl = threadIdx.x >> 6, u = threadIdx.x & 63;
  float2* row = data + ((size_t)blockIdx.x*4 + rl)*NSZ;
  #pragma unroll
  for (int k=0;k<6;k++) buf0[rl][u+64*k] = row[u+64*k];
  __syncthreads();
  fft384<1,DIR>(&buf0[rl][0], &buf1[rl][0], u, tw);
  #pragma unroll
  for (int k=0;k<6;k++) row[u+64*k] = buf0[rl][u+64*k];
}

// ---------------- column-pass FFT kernels (8 cols/block, 512 threads) -------
template<int DIR>
__global__ __launch_bounds__(512) void k_fft_cols(float2* data){
  __shared__ float2 buf0[NSZ*9], buf1[NSZ*9];
  __shared__ float2 tw[NSZ];
  init_tw(tw);
  int img = blockIdx.x / 48, cg = blockIdx.x % 48;
  float2* base = data + (size_t)img*NPIX + (size_t)cg*8;
  int j = threadIdx.x & 7, r0 = threadIdx.x >> 3;
  #pragma unroll
  for (int k=0;k<6;k++){
    int r = r0 + 64*k;
    buf0[r*9 + j] = base[(size_t)r*NSZ + j];
  }
  __syncthreads();
  int cc = threadIdx.x >> 6, u = threadIdx.x & 63;
  fft384<9,DIR>(&buf0[cc], &buf1[cc], u, tw);
  #pragma unroll
  for (int k=0;k<6;k++){
    int r = r0 + 64*k;
    base[(size_t)r*NSZ + j] = buf0[r*9 + j];
  }
}

// FUSED: fwd col FFT + spectral multiply + inv col FFT, in place (grid nimg*48;
// data img and fm img aligned 1:1)
__global__ __launch_bounds__(512) void k_fused_cols(float2* data,
    const float2* __restrict__ fm){
  __shared__ float2 buf0[NSZ*9], buf1[NSZ*9];
  __shared__ float2 tw[NSZ];
  init_tw(tw);
  int img = blockIdx.x / 48, cg = blockIdx.x % 48;
  size_t boff = (size_t)img*NPIX + (size_t)cg*8;
  int j = threadIdx.x & 7, r0 = threadIdx.x >> 3;
  #pragma unroll
  for (int k=0;k<6;k++){
    int r = r0 + 64*k;
    buf0[r*9 + j] = data[boff + (size_t)r*NSZ + j];
  }
  __syncthreads();
  int cc = threadIdx.x >> 6, u = threadIdx.x & 63;
  fft384<9,1>(&buf0[cc], &buf1[cc], u, tw);
  const float2* fbase = fm + boff;
  #pragma unroll
  for (int k=0;k<6;k++){
    int r = r0 + 64*k;
    buf0[r*9 + j] = cmul_(buf0[r*9 + j], fbase[(size_t)r*NSZ + j]);
  }
  __syncthreads();
  fft384<9,-1>(&buf0[cc], &buf1[cc], u, tw);
  #pragma unroll
  for (int k=0;k<6;k++){
    int r = r0 + 64*k;
    data[boff + (size_t)r*NSZ + j] = buf0[r*9 + j];
  }
}

// inverse col FFT with multiply on load, single (c,b) pair: grid 16*48
__global__ __launch_bounds__(512) void k_mulinv_cols(const float2* __restrict__ src,
    const float2* __restrict__ fm, float2* __restrict__ dst){
  __shared__ float2 buf0[NSZ*9], buf1[NSZ*9];
  __shared__ float2 tw[NSZ];
  init_tw(tw);
  int img = blockIdx.x / 48, cg = blockIdx.x % 48;
  size_t boff = (size_t)img*NPIX + (size_t)cg*8;
  const float2* fbase = fm + boff;
  int j = threadIdx.x & 7, r0 = threadIdx.x >> 3;
  #pragma unroll
  for (int k=0;k<6;k++){
    int r = r0 + 64*k;
    buf0[r*9 + j] = cmul_(src[boff + (size_t)r*NSZ + j], fbase[(size_t)r*NSZ + j]);
  }
  __syncthreads();
  int cc = threadIdx.x >> 6, u = threadIdx.x & 63;
  fft384<9,-1>(&buf0[cc], &buf1[cc], u, tw);
  #pragma unroll
  for (int k=0;k<6;k++){
    int r = r0 + 64*k;
    dst[boff + (size_t)r*NSZ + j] = buf0[r*9 + j];
  }
}

// merged across all 6 (c,b) pairs: grid 6*16*48
__global__ __launch_bounds__(512) void k_mulinv_all(const float2* __restrict__ S,
    const float2* __restrict__ F, float2* __restrict__ L){
  __shared__ float2 buf0[NSZ*9], buf1[NSZ*9];
  __shared__ float2 tw[NSZ];
  init_tw(tw);
  int t = blockIdx.x;
  int cg = t % 48, d = (t/48) & 15, p = t / (48*16);
  int c = p >> 1, b = p & 1;
  size_t coff = (size_t)cg*8;
  const float2* src   = S + ((size_t)(b*ND+d)*NPIX + coff);
  const float2* fbase = F + ((size_t)(c*ND+d)*NPIX + coff);
  float2*       dst   = L + ((size_t)(p*ND+d)*NPIX + coff);
  int j = threadIdx.x & 7, r0 = threadIdx.x >> 3;
  #pragma unroll
  for (int k=0;k<6;k++){
    int r = r0 + 64*k;
    buf0[r*9 + j] = cmul_(src[(size_t)r*NSZ + j], fbase[(size_t)r*NSZ + j]);
  }
  __syncthreads();
  int cc = threadIdx.x >> 6, u = threadIdx.x & 63;
  fft384<9,-1>(&buf0[cc], &buf1[cc], u, tw);
  #pragma unroll
  for (int k=0;k<6;k++){
    int r = r0 + 64*k;
    dst[(size_t)r*NSZ + j] = buf0[r*9 + j];
  }
}

// ---------------- FUSED inverse row FFT + occlusion compositing -------------
// L imgs (x-spectral): p*16+d layout; V spatial: (vc*16+d); out[(b*3+c)].
// c0>=0: single pair mode (p=0, c=c0, b=b0, V index base cv). Else p from grid.
__global__ __launch_bounds__(256) void k_rows_combine(const float2* __restrict__ L,
    const float2* __restrict__ V, float* __restrict__ out, int c0, int b0, int cv0){
  __shared__ float2 buf0[4][NSZ], buf1[4][NSZ];
  __shared__ float2 tw[NSZ];
  init_tw(tw);
  int p, grp;
  if (c0 >= 0){ p = 0; grp = blockIdx.x; }
  else { p = blockIdx.x / 96; grp = blockIdx.x % 96; }
  int c  = (c0 >= 0) ? c0  : (p >> 1);
  int b  = (c0 >= 0) ? b0  : (p & 1);
  int cv = (c0 >= 0) ? cv0 : c;
  int rl = threadIdx.x >> 6, u = threadIdx.x & 63;
  int y  = grp*4 + rl;
  float over[6], acc[6];
  #pragma unroll
  for (int k=0;k<6;k++){ over[k]=1.f; acc[k]=0.f; }
  for (int d=0; d<ND; d++){
    const float2* lrow = L + ((size_t)(p*ND + d)*NPIX + (size_t)y*NSZ);
    #pragma unroll
    for (int k=0;k<6;k++) buf0[rl][u+64*k] = lrow[u+64*k];
    __syncthreads();
    fft384<1,-1>(&buf0[rl][0], &buf1[rl][0], u, tw);
    const float2* vrow = V + ((size_t)(cv*ND + d)*NPIX + (size_t)y*NSZ);
    #pragma unroll
    for (int k=0;k<6;k++){
      float2 ac = buf0[rl][u+64*k];
      float2 vv = vrow[u+64*k];
      float Vb = (b==0) ? vv.x : vv.y;
      float ic = 1.f/(ac.y + EPSV);
      acc[k]  += over[k] * (Vb * ic);
      over[k] *= (1.f - ac.x * ic);
    }
  }
  float* orow = out + ((size_t)(b*3 + c)*NPIX + (size_t)y*NSZ);
  #pragma unroll
  for (int k=0;k<6;k++) orow[u+64*k] = acc[k];
}

extern "C" void kernel_launch(void* const* d_in, const int* in_sizes, int n_in,
                              void* d_out, int out_size, void* d_ws, size_t ws_size,
                              hipStream_t stream){
  const float* img   = (const float*)d_in[0];   // (2,3,384,384) f32
  const float* depth = (const float*)d_in[1];   // (2,1,384,384) f32
  const void*  h1d   = d_in[2];                 // (1024,) f64 or f32
  const void*  amp   = d_in[3];                 // (3,16,1024)
  const void*  pph   = d_in[4];                 // (3,16,1024)
  const void*  Hm    = d_in[5];                 // (3,1024,194)
  const void*  rg    = d_in[6];                 // (3,194)
  const void*  rs    = d_in[7];                 // (3,192,192)
  float* out = (float*)d_out;
  (void)in_sizes; (void)n_in; (void)out_size;

  char* ws = (char*)d_ws;
  size_t off = 0;
  auto take = [&](size_t b)->char*{ char* p = ws + off; off += (b + 255) & ~(size_t)255; return p; };
  // common small buffers
  int*    flag  = (int*)   take(256);
  double* psf1d = (double*)take((size_t)48*NG*8);      //  74.5 KB
  double* sums  = (double*)take((size_t)48*8);
  double* acs   = (double*)take((size_t)48*MS2*8);     //  384 KB
  double* ass   = (double*)take((size_t)48*MS2*8);     //  384 KB
  size_t off_common = off;

  // ---- tier footprints (computed, no allocation side effects yet) ----
  const size_t szQ48 = (size_t)48*QPIX*4, szQ16 = (size_t)16*QPIX*4;
  const size_t szI16 = (size_t)16*NPIX*8;              // 16 complex images
  // T0: q16 + F16 + V16 + L16            (~59.8 MB total)
  // T1: q48 + F48 + V48 + S32 + L16      (~178 MB)
  // T2: q48 + F48 + V48 + S32 + L96      (~272 MB)
  size_t t0_need = off_common + ((szQ16+255)&~255ull) + 3*((szI16+255)&~255ull);
  size_t t1_need = off_common + ((szQ48+255)&~255ull) + 3*((szI16*3+255)&~255ull)
                   + ((szI16*2+255)&~255ull) + ((szI16+255)&~255ull);
  size_t t2_need = t1_need + szI16*5;    // L grows 16 -> 96 images

  int tier = (ws_size >= t2_need) ? 2 : (ws_size >= t1_need) ? 1
           : (ws_size >= t0_need) ? 0 : -1;
  if (tier < 0) return;   // clean absmax failure, not a fault

  // shared prologue: dtype detect, trig, two-stage dot (partials alias onto q)
  k_detect<<<1, 1, 0, stream>>>(rg, flag);
  hipMemsetAsync(sums, 0, 48*8, stream);
  k_trig<<<48, 256, 0, stream>>>(h1d, amp, pph, flag, acs, ass);

  if (tier == 0){
    float*  q  = (float*) take(szQ16);
    float2* Fc = (float2*)take(szI16);
    float2* Vc = (float2*)take(szI16);
    float2* L0 = (float2*)take(szI16);
    double2* part = (double2*)q;   // 1.19 MB <= 2.36 MB, consumed before q written
    k_dotA<<<48*8, 256, 0, stream>>>(acs, ass, Hm, flag, part);
    k_dotB<<<(48*NG+255)/256, 256, 0, stream>>>(part, psf1d);
    for (int c=0; c<3; c++){
      k_interp<<<16*144, 256, 0, stream>>>(psf1d + (size_t)c*16*NG, rg, rs, flag,
                                           q, sums + (size_t)c*16, c*16);
      k_rows_psf<<<16*96, 256, 0, stream>>>(q, sums + (size_t)c*16, Fc);
      k_fft_cols<1><<<16*48, 512, 0, stream>>>(Fc);
      k_rows_V<<<16*96, 256, 0, stream>>>(img, depth, c*16, Vc);
      k_fused_cols<<<16*48, 512, 0, stream>>>(Vc, Fc);
      k_fft_rows<-1><<<16*96, 256, 0, stream>>>(Vc);
      for (int b=0; b<2; b++){
        k_rows_LC<<<16*96, 256, 0, stream>>>(depth, b*16, L0);
        k_fused_cols<<<16*48, 512, 0, stream>>>(L0, Fc);
        k_rows_combine<<<96, 256, 0, stream>>>(L0, Vc, out, c, b, 0);
      }
    }
    return;
  }

  // tiers 1/2: fully merged across channels
  float*  q = (float*) take(szQ48);
  float2* F = (float2*)take(szI16*3);
  float2* V = (float2*)take(szI16*3);
  float2* S = (float2*)take(szI16*2);
  float2* L = (float2*)take(tier==2 ? szI16*6 : szI16);
  double2* part = (double2*)q;
  k_dotA<<<48*8, 256, 0, stream>>>(acs, ass, Hm, flag, part);
  k_dotB<<<(48*NG+255)/256, 256, 0, stream>>>(part, psf1d);

  k_interp<<<48*144, 256, 0, stream>>>(psf1d, rg, rs, flag, q, sums, 0);
  k_rows_psf<<<48*96, 256, 0, stream>>>(q, sums, F);
  k_fft_cols<1><<<48*48, 512, 0, stream>>>(F);
  k_rows_V<<<48*96, 256, 0, stream>>>(img, depth, 0, V);
  k_fused_cols<<<48*48, 512, 0, stream>>>(V, F);
  k_fft_rows<-1><<<48*96, 256, 0, stream>>>(V);
  k_rows_LC<<<32*96, 256, 0, stream>>>(depth, 0, S);
  k_fft_cols<1><<<32*48, 512, 0, stream>>>(S);

  if (tier == 2){
    k_mulinv_all<<<6*16*48, 512, 0, stream>>>(S, F, L);
    k_rows_combine<<<6*96, 256, 0, stream>>>(L, V, out, -1, -1, -1);
  } else {
    for (int p=0; p<6; p++){
      int c = p >> 1, b = p & 1;
      k_mulinv_cols<<<16*48, 512, 0, stream>>>(S + (size_t)b*16*NPIX,
                                               F + (size_t)c*16*NPIX, L);
      k_rows_combine<<<96, 256, 0, stream>>>(L, V, out, c, b, c);
    }
  }
}

// Round 6
// 445.773 us; speedup vs baseline: 1.9579x; 1.5850x over previous
//
#include <hip/hip_runtime.h>
#include <math.h>

#define ND 16
#define NSZ 384
#define NHALF 192
#define NPIX 147456    // 384*384
#define QPIX 36864     // 192*192
#define MS2 1024
#define NG 194
#define EPSV 0.001f

// load element i of a buffer that is f64 (flag=1) or f32 (flag=0)
__device__ __forceinline__ double ld64(const void* p, long i, int f){
  return f ? ((const double*)p)[i] : (double)((const float*)p)[i];
}

// ---------------- dtype detect ----------------------------------------------
__global__ void k_detect(const void* rg, int* flag){
  double d = ((const double*)rg)[1];
  *flag = (fabs(d) < 1.0e9) ? 1 : 0;
}

// ---------------- twiddles (SoA): twr[j]=cos, twi[j]=-sin (e^{-2pi i j/384})
__device__ __forceinline__ void init_tws(float* twr, float* twi){
  for (int j=(int)threadIdx.x; j<NSZ; j+=(int)blockDim.x){
    double s,c; sincos((2.0*M_PI/384.0)*(double)j, &s, &c);
    twr[j]=(float)c; twi[j]=(float)(-s);
  }
}

// ---------------- SoA Stockham FFT, N=384=3*2^7, 64 threads/transform -------
// element p at [p*STR] relative to passed base pointers (unit folded into base).
// 8 stages (even # of buffer swaps) -> result back in (xr,xi).
template<int STR,int DIR>
__device__ __forceinline__ void fft384s(float* xr,float* xi,float* yr,float* yi,
                                        int u,const float* twr,const float* twi){
  const float KH = (DIR>0)?0.86602540378443865f:-0.86602540378443865f;
  float *Xr=xr,*Xi=xi,*Yr=yr,*Yi=yi;
  #pragma unroll
  for (int i0=0;i0<128;i0+=64){
    int p=i0+u;
    float ar=Xr[p*STR],ai=Xi[p*STR];
    float br=Xr[(p+128)*STR],bi=Xi[(p+128)*STR];
    float cr=Xr[(p+256)*STR],ci=Xi[(p+256)*STR];
    float t1r=br+cr,t1i=bi+ci;
    float y0r=ar+t1r,y0i=ai+t1i;
    float t2r=ar-0.5f*t1r,t2i=ai-0.5f*t1i;
    float bdr=br-cr,bdi=bi-ci;
    float t3r=KH*bdi,t3i=-KH*bdr;
    float w1r=twr[p],     w1i=(DIR>0)?twi[p]:-twi[p];
    float w2r=twr[2*p],   w2i=(DIR>0)?twi[2*p]:-twi[2*p];
    float y1r=t2r+t3r,y1i=t2i+t3i;
    float y2r=t2r-t3r,y2i=t2i-t3i;
    Yr[(3*p  )*STR]=y0r;             Yi[(3*p  )*STR]=y0i;
    Yr[(3*p+1)*STR]=y1r*w1r-y1i*w1i; Yi[(3*p+1)*STR]=y1r*w1i+y1i*w1r;
    Yr[(3*p+2)*STR]=y2r*w2r-y2i*w2i; Yi[(3*p+2)*STR]=y2r*w2i+y2i*w2r;
  }
  __syncthreads();
  { float*t; t=Xr;Xr=Yr;Yr=t; t=Xi;Xi=Yi;Yi=t; }
  #pragma unroll
  for (int st=0; st<7; st++){
    const int s = 3<<st;
    #pragma unroll
    for (int i0=0;i0<192;i0+=64){
      int i=i0+u, p=i/s, t=p*s;
      float ar=Xr[i*STR],ai=Xi[i*STR];
      float br=Xr[(i+192)*STR],bi=Xi[(i+192)*STR];
      float wr=twr[t], wi=(DIR>0)?twi[t]:-twi[t];
      float sur=ar+br,sui=ai+bi;
      float dr=ar-br,di=ai-bi;
      int o=i+t;
      Yr[o*STR]=sur;             Yi[o*STR]=sui;
      Yr[(o+s)*STR]=dr*wr-di*wi; Yi[(o+s)*STR]=dr*wi+di*wr;
    }
    __syncthreads();
    { float*t2; t2=Xr;Xr=Yr;Yr=t2; t2=Xi;Xi=Yi;Yi=t2; }
  }
}

// ---------------- K1a: trig precompute --------------------------------------
__global__ __launch_bounds__(256) void k_trig(const void* __restrict__ h1d,
    const void* __restrict__ amp, const void* __restrict__ pph,
    const int* __restrict__ flagp, double* __restrict__ acs, double* __restrict__ ass){
  int wd = blockIdx.x;            // w*16+d
  int w = wd >> 4;
  int f = *flagp;
  double wl = (w==0) ? 6.32e-07 : (w==1 ? 5.5e-07 : 4.5e-07);
  double um2 = (wl*1e6)*(wl*1e6);
  double n_idx = 1.5375 + 0.00829045/um2 - 0.000211046/(um2*um2);
  double coef = (2.0*M_PI/wl)*(n_idx-1.0);
  for (int m = (int)threadIdx.x; m < MS2; m += 256){
    double h = ld64(h1d, m, f);
    double a = ld64(amp, (long)wd*MS2 + m, f);
    double p = ld64(pph, (long)wd*MS2 + m, f);
    double s,c; sincos(coef*h + p, &s, &c);
    acs[(size_t)wd*MS2 + m] = a*c;
    ass[(size_t)wd*MS2 + m] = a*s;
  }
}

// ---------------- K1b/K1c: two-stage dot ------------------------------------
__global__ __launch_bounds__(256) void k_dotA(const double* __restrict__ acs,
    const double* __restrict__ ass, const void* __restrict__ Hm,
    const int* __restrict__ flagp, double2* __restrict__ part){
  int wd = blockIdx.x >> 3, ch = blockIdx.x & 7;
  int w = wd >> 4;
  int f = *flagp;
  int m0 = ch << 7;
  __shared__ double sac[128], sas[128];
  int tid = (int)threadIdx.x;
  if (tid < 128){
    sac[tid] = acs[(size_t)wd*MS2 + m0 + tid];
    sas[tid] = ass[(size_t)wd*MS2 + m0 + tid];
  }
  __syncthreads();
  int r = tid;
  if (r < NG){
    double sr=0.0, si=0.0;
    if (f){
      const double* Hw = (const double*)Hm + ((size_t)w*MS2 + m0)*NG + r;
      #pragma unroll 4
      for (int m=0;m<128;m++){
        double h = Hw[(size_t)m*NG];
        sr += sac[m]*h; si += sas[m]*h;
      }
    } else {
      const float* Hw = (const float*)Hm + ((size_t)w*MS2 + m0)*NG + r;
      #pragma unroll 4
      for (int m=0;m<128;m++){
        double h = (double)Hw[(size_t)m*NG];
        sr += sac[m]*h; si += sas[m]*h;
      }
    }
    part[(size_t)blockIdx.x*NG + r] = make_double2(sr, si);
  }
}

__global__ __launch_bounds__(256) void k_dotB(const double2* __restrict__ part,
    double* __restrict__ psf1d){
  int t = blockIdx.x*256 + (int)threadIdx.x;
  if (t >= 48*NG) return;
  int wd = t / NG, r = t - wd*NG;
  double sr=0.0, si=0.0;
  for (int ch=0; ch<8; ch++){
    double2 pp = part[(size_t)(wd*8+ch)*NG + r];
    sr += pp.x; si += pp.y;
  }
  psf1d[t] = sr*sr + si*si;
}

// ---------------- K2: interp onto quadrant + per-img quadrant sum -----------
__global__ __launch_bounds__(256) void k_interp(const double* __restrict__ psf1d_b,
    const void* __restrict__ rg, const void* __restrict__ rs,
    const int* __restrict__ flagp, float* __restrict__ q,
    double* __restrict__ sums_b){
  int wdl = blockIdx.x / 144, blk = blockIdx.x % 144;
  int c = wdl >> 4;
  int pix = blk*256 + (int)threadIdx.x;     // 0..36863
  int f = *flagp;
  const double* v = psf1d_b + (size_t)wdl*NG;
  long gbase = (long)c*NG;
  double rho = ld64(rs, (long)c*QPIX + pix, f);
  double g0 = ld64(rg, gbase, f);
  double delta = ld64(rg, gbase+1, f) - g0;
  int i = (int)floor((rho-g0)/delta);
  if (i < 0) i = 0; if (i > 192) i = 192;
  double gi  = ld64(rg, gbase+i,   f);
  double gi1 = ld64(rg, gbase+i+1, f);
  if (i > 0  && rho < gi)  { i--; gi1 = gi; gi = ld64(rg, gbase+i, f); }
  else if (i < 192 && rho > gi1){ i++; gi = gi1; gi1 = ld64(rg, gbase+i+1, f); }
  double gl = ld64(rg, gbase+NG-1, f);
  double val;
  if (rho <= g0)      val = v[0];
  else if (rho >= gl) val = v[NG-1];
  else { double t = (rho-gi)/(gi1-gi); val = v[i] + (v[i+1]-v[i])*t; }
  if (val < 0.0) val = 0.0;
  q[(size_t)wdl*QPIX + pix] = (float)val;
  __shared__ double red[256];
  red[threadIdx.x] = val;
  __syncthreads();
  for (int s=128; s>0; s>>=1){
    if ((int)threadIdx.x < s) red[threadIdx.x] += red[threadIdx.x+s];
    __syncthreads();
  }
  if (threadIdx.x==0) atomicAdd(&sums_b[wdl], red[0]);
}

// ---------------- merged forward ROW pass -----------------------------------
// roles: [0,1152) psf packed-pair rows -> real Rr; [1152,1152+4608) V rows;
// rest LC rows. 256 threads, 4 FFT units (1 wave each), SoA stride 5.
__global__ __launch_bounds__(256) void k_rows_fwd(
    const float* __restrict__ q, const double* __restrict__ sums,
    float* __restrict__ Rr, const float* __restrict__ img,
    const float* __restrict__ depth, float2* __restrict__ V,
    float2* __restrict__ S){
  __shared__ float b0r[NSZ*5], b0i[NSZ*5], b1r[NSZ*5], b1i[NSZ*5];
  __shared__ float twr[NSZ], twi[NSZ];
  init_tws(twr, twi);
  int bi = blockIdx.x;
  int rl = (int)threadIdx.x>>6, u = (int)threadIdx.x&63;
  float *xr=b0r+rl, *xi=b0i+rl, *yr=b1r+rl, *yi=b1i+rl;
  if (bi < 48*24){
    // PSF: rows y0=8t+2rl (re), y0+1 (im); all <192. Output real Rr[img][y][kx].
    int imgi = bi/24, t = bi%24;
    int y0 = t*8 + 2*rl;
    float sc = (float)(1.0/(4.0*sums[imgi]*147456.0));
    const float* q0 = q + ((size_t)imgi*QPIX + (size_t)y0*NHALF);
    const float* q1 = q0 + NHALF;
    #pragma unroll
    for (int k=0;k<6;k++){
      int x = u+64*k;
      int gx = (x<NHALF)? x : (383-x);
      xr[x*5] = q0[gx]*sc;
      xi[x*5] = q1[gx]*sc;
    }
    __syncthreads();
    fft384s<5,1>(xr,xi,yr,yi,u,twr,twi);
    const float PC=0.86602540378443865f, PS=-0.5f;   // e^{-i pi/6}
    float s0,c0; __sincosf((float)M_PI*(float)u/384.0f,&s0,&c0);
    float phr=c0, phi=-s0;                            // e^{-i pi kx/384}
    float* o0 = Rr + ((size_t)imgi*192 + y0)*NSZ;
    float* o1 = o0 + NSZ;
    #pragma unroll
    for (int k=0;k<6;k++){
      int kx = u+64*k;
      int m  = kx ? (384-kx) : 0;
      float Zr=xr[kx*5], Zi=xi[kx*5], Zmr=xr[m*5], Zmi=xi[m*5];
      float Ar=0.5f*(Zr+Zmr), Ai=0.5f*(Zi-Zmi);
      float Br=0.5f*(Zi+Zmi), Bi=-0.5f*(Zr-Zmr);
      o0[kx] = Ar*phr - Ai*phi;
      o1[kx] = Br*phr - Bi*phi;
      float nr=phr*PC-phi*PS, ni=phr*PS+phi*PC; phr=nr; phi=ni;
    }
  } else if (bi < 48*24 + 48*96){
    int i2 = bi - 48*24;
    int im48 = i2/96, grp = i2%96;
    int c = im48>>4, d = im48&15;
    int y = grp*4 + rl;
    const float* i0 = img + (((size_t)0*3+c)*NPIX + (size_t)y*NSZ);
    const float* i1 = img + (((size_t)1*3+c)*NPIX + (size_t)y*NSZ);
    const float* d0 = depth + (size_t)y*NSZ;
    const float* d1 = depth + (size_t)NPIX + (size_t)y*NSZ;
    #pragma unroll
    for (int k=0;k<6;k++){
      int x=u+64*k;
      int ia=(int)floorf(d0[x]*16.f); ia=ia<0?0:(ia>15?15:ia);
      int ib=(int)floorf(d1[x]*16.f); ib=ib<0?0:(ib>15?15:ib);
      xr[x*5] = (ia==d)? i0[x] : 0.f;
      xi[x*5] = (ib==d)? i1[x] : 0.f;
    }
    __syncthreads();
    fft384s<5,1>(xr,xi,yr,yi,u,twr,twi);
    float2* orow = V + ((size_t)im48*NPIX + (size_t)y*NSZ);
    #pragma unroll
    for (int k=0;k<6;k++){ int x=u+64*k; orow[x]=make_float2(xr[x*5],xi[x*5]); }
  } else {
    int i3 = bi - 48*24 - 48*96;
    int im32 = i3/96, grp = i3%96;
    int b = im32>>4, d = im32&15;
    int y = grp*4+rl;
    const float* dr_ = depth + ((size_t)b*NPIX + (size_t)y*NSZ);
    #pragma unroll
    for (int k=0;k<6;k++){
      int x=u+64*k;
      int idx=(int)floorf(dr_[x]*16.f); idx=idx<0?0:(idx>15?15:idx);
      xr[x*5]=(idx==d)?1.f:0.f;
      xi[x*5]=(idx>=d)?1.f:0.f;
    }
    __syncthreads();
    fft384s<5,1>(xr,xi,yr,yi,u,twr,twi);
    float2* orow = S + ((size_t)im32*NPIX + (size_t)y*NSZ);
    #pragma unroll
    for (int k=0;k<6;k++){ int x=u+64*k; orow[x]=make_float2(xr[x*5],xi[x*5]); }
  }
}

// ---------------- cols pass for F: real in (mirrored), real out -------------
// 512 thr, 8 FFT units = 16 packed columns/block; grid 48*24.
__global__ __launch_bounds__(512) void k_cols_F(const float* __restrict__ Rr,
    float* __restrict__ Rc){
  __shared__ float b0r[NSZ*9], b0i[NSZ*9], b1r[NSZ*9], b1i[NSZ*9];
  __shared__ float twr[NSZ], twi[NSZ];
  init_tws(twr,twi);
  int imgi = blockIdx.x/24, cg = blockIdx.x%24;
  int j16 = (int)threadIdx.x&15, r0 = (int)threadIdx.x>>4;   // r0 in [0,32)
  int uu = j16>>1;
  const float* rbase = Rr + (size_t)imgi*192*NSZ + cg*16 + j16;
  #pragma unroll
  for (int k=0;k<12;k++){
    int y = r0 + 32*k;
    int gy = (y<NHALF)? y : (383-y);
    float v = rbase[(size_t)gy*NSZ];
    if (j16&1) b0i[y*9+uu]=v; else b0r[y*9+uu]=v;
  }
  __syncthreads();
  int cc = (int)threadIdx.x>>6, u = (int)threadIdx.x&63;
  fft384s<9,1>(b0r+cc,b0i+cc,b1r+cc,b1i+cc,u,twr,twi);
  // unpack packed pair, remove e^{i pi ky/384}, store real Rc[img][ky][kx]
  const float PC=0.96592582628906829f, PS=-0.25881904510252076f; // e^{-i pi/12}
  float s0,c0; __sincosf((float)M_PI*(float)r0/384.f,&s0,&c0);
  float phr=c0, phi=-s0;
  float* ob = Rc + (size_t)imgi*NPIX + cg*16 + j16;
  #pragma unroll
  for (int k=0;k<12;k++){
    int ky=r0+32*k;
    int m = ky ? (384-ky) : 0;
    float Zr=b0r[ky*9+uu], Zi=b0i[ky*9+uu], Zmr=b0r[m*9+uu], Zmi=b0i[m*9+uu];
    float Cr,Ci;
    if (j16&1){ Cr=0.5f*(Zi+Zmi); Ci=-0.5f*(Zr-Zmr); }
    else      { Cr=0.5f*(Zr+Zmr); Ci= 0.5f*(Zi-Zmi); }
    ob[(size_t)ky*NSZ] = Cr*phr - Ci*phi;
    float nr=phr*PC-phi*PS, ni=phr*PS+phi*PC; phr=nr; phi=ni;
  }
}

// ---------------- forward cols in place (S): 8 cols/block, grid 32*48 -------
__global__ __launch_bounds__(512) void k_cols_S(float2* __restrict__ S){
  __shared__ float b0r[NSZ*9], b0i[NSZ*9], b1r[NSZ*9], b1i[NSZ*9];
  __shared__ float twr[NSZ], twi[NSZ];
  init_tws(twr,twi);
  int imgi = blockIdx.x/48, cg = blockIdx.x%48;
  size_t boff = (size_t)imgi*NPIX + (size_t)cg*8;
  int j = (int)threadIdx.x&7, r0 = (int)threadIdx.x>>3;
  #pragma unroll
  for (int k=0;k<6;k++){
    int r=r0+64*k;
    float2 v = S[boff + (size_t)r*NSZ + j];
    b0r[r*9+j]=v.x; b0i[r*9+j]=v.y;
  }
  __syncthreads();
  int cc=(int)threadIdx.x>>6, u=(int)threadIdx.x&63;
  fft384s<9,1>(b0r+cc,b0i+cc,b1r+cc,b1i+cc,u,twr,twi);
  #pragma unroll
  for (int k=0;k<6;k++){
    int r=r0+64*k;
    S[boff+(size_t)r*NSZ+j] = make_float2(b0r[r*9+j], b0i[r*9+j]);
  }
}

// ---------------- FUSED: fwd cols + (Rc*phase) mul + inv cols, in place (V) -
__global__ __launch_bounds__(512) void k_fused(float2* __restrict__ V,
    const float* __restrict__ Rc){
  __shared__ float b0r[NSZ*9], b0i[NSZ*9], b1r[NSZ*9], b1i[NSZ*9];
  __shared__ float twr[NSZ], twi[NSZ];
  init_tws(twr,twi);
  int imgi = blockIdx.x/48, cg = blockIdx.x%48;
  size_t boff = (size_t)imgi*NPIX + (size_t)cg*8;
  int j = (int)threadIdx.x&7, r0 = (int)threadIdx.x>>3;
  #pragma unroll
  for (int k=0;k<6;k++){
    int r=r0+64*k;
    float2 v = V[boff + (size_t)r*NSZ + j];
    b0r[r*9+j]=v.x; b0i[r*9+j]=v.y;
  }
  __syncthreads();
  int cc=(int)threadIdx.x>>6, u=(int)threadIdx.x&63;
  fft384s<9,1>(b0r+cc,b0i+cc,b1r+cc,b1i+cc,u,twr,twi);
  // multiply by F = Rc * e^{+i pi (kx+ky)/384}
  const float PC=0.86602540378443865f, PS=0.5f;   // e^{+i pi/6}
  int kx = cg*8+j;
  float s0,c0; __sincosf((float)M_PI*(float)(kx+r0)/384.f,&s0,&c0);
  float phr=c0, phi=s0;
  const float* rb = Rc + (size_t)imgi*NPIX + kx;
  #pragma unroll
  for (int k=0;k<6;k++){
    int r=r0+64*k;
    float R = rb[(size_t)r*NSZ];
    float fr=R*phr, fi=R*phi;
    float br=b0r[r*9+j], bi2=b0i[r*9+j];
    b0r[r*9+j] = br*fr - bi2*fi;
    b0i[r*9+j] = br*fi + bi2*fr;
    float nr=phr*PC-phi*PS, ni=phr*PS+phi*PC; phr=nr; phi=ni;
  }
  __syncthreads();
  fft384s<9,-1>(b0r+cc,b0i+cc,b1r+cc,b1i+cc,u,twr,twi);
  #pragma unroll
  for (int k=0;k<6;k++){
    int r=r0+64*k;
    V[boff+(size_t)r*NSZ+j] = make_float2(b0r[r*9+j], b0i[r*9+j]);
  }
}

// ---------------- mul + inverse cols: S-spec * F -> L (x-spectral) ----------
// grid npairs*16*48; pl local pair index into L, p=p0+pl global (c,b).
__global__ __launch_bounds__(512) void k_mulinv(const float2* __restrict__ S,
    const float* __restrict__ Rc, float2* __restrict__ L, int p0){
  __shared__ float b0r[NSZ*9], b0i[NSZ*9], b1r[NSZ*9], b1i[NSZ*9];
  __shared__ float twr[NSZ], twi[NSZ];
  init_tws(twr,twi);
  int t = blockIdx.x;
  int cg = t%48, d=(t/48)&15, pl=t/(48*16);
  int p = p0+pl, c=p>>1, b=p&1;
  const float2* src = S  + ((size_t)(b*ND+d)*NPIX + (size_t)cg*8);
  const float*  rb  = Rc + ((size_t)(c*ND+d)*NPIX + cg*8);
  float2*       dst = L  + ((size_t)(pl*ND+d)*NPIX + (size_t)cg*8);
  int j = (int)threadIdx.x&7, r0 = (int)threadIdx.x>>3;
  const float PC=0.86602540378443865f, PS=0.5f;   // e^{+i pi/6}
  int kx = cg*8+j;
  float s0,c0; __sincosf((float)M_PI*(float)(kx+r0)/384.f,&s0,&c0);
  float phr=c0, phi=s0;
  #pragma unroll
  for (int k=0;k<6;k++){
    int r=r0+64*k;
    float2 v = src[(size_t)r*NSZ + j];
    float R = rb[(size_t)r*NSZ + j - j];   // rb already offset by kx? no: rb = ..+cg*8
    R = rb[(size_t)r*NSZ + j];
    float fr=R*phr, fi=R*phi;
    b0r[r*9+j] = v.x*fr - v.y*fi;
    b0i[r*9+j] = v.x*fi + v.y*fr;
    float nr=phr*PC-phi*PS, ni=phr*PS+phi*PC; phr=nr; phi=ni;
  }
  __syncthreads();
  int cc=(int)threadIdx.x>>6, u=(int)threadIdx.x&63;
  fft384s<9,-1>(b0r+cc,b0i+cc,b1r+cc,b1i+cc,u,twr,twi);
  #pragma unroll
  for (int k=0;k<6;k++){
    int r=r0+64*k;
    dst[(size_t)r*NSZ+j] = make_float2(b0r[r*9+j], b0i[r*9+j]);
  }
}

// ---------------- inverse row FFT in place (V) ------------------------------
__global__ __launch_bounds__(256) void k_rowsinv(float2* __restrict__ data){
  __shared__ float b0r[NSZ*5], b0i[NSZ*5], b1r[NSZ*5], b1i[NSZ*5];
  __shared__ float twr[NSZ], twi[NSZ];
  init_tws(twr,twi);
  int rl=(int)threadIdx.x>>6, u=(int)threadIdx.x&63;
  float *xr=b0r+rl,*xi=b0i+rl,*yr=b1r+rl,*yi=b1i+rl;
  float2* row = data + ((size_t)blockIdx.x*4 + rl)*NSZ;
  #pragma unroll
  for (int k=0;k<6;k++){ int x=u+64*k; float2 v=row[x]; xr[x*5]=v.x; xi[x*5]=v.y; }
  __syncthreads();
  fft384s<5,-1>(xr,xi,yr,yi,u,twr,twi);
  #pragma unroll
  for (int k=0;k<6;k++){ int x=u+64*k; row[x]=make_float2(xr[x*5],xi[x*5]); }
}

// ---------------- fused inverse row FFT + occlusion compositing -------------
// grid npairs*96; L local-pair indexed; V spatial (c*16+d) batch-packed.
__global__ __launch_bounds__(256) void k_combine(const float2* __restrict__ L,
    const float2* __restrict__ V, float* __restrict__ out, int p0){
  __shared__ float b0r[NSZ*5], b0i[NSZ*5], b1r[NSZ*5], b1i[NSZ*5];
  __shared__ float twr[NSZ], twi[NSZ];
  init_tws(twr,twi);
  int pl = blockIdx.x/96, grp = blockIdx.x%96;
  int p = p0+pl, c=p>>1, b=p&1;
  int rl=(int)threadIdx.x>>6, u=(int)threadIdx.x&63;
  float *xr=b0r+rl,*xi=b0i+rl,*yr=b1r+rl,*yi=b1i+rl;
  int y = grp*4+rl;
  float over[6], acc[6];
  #pragma unroll
  for (int k=0;k<6;k++){ over[k]=1.f; acc[k]=0.f; }
  for (int d=0; d<ND; d++){
    const float2* lrow = L + ((size_t)(pl*ND+d)*NPIX + (size_t)y*NSZ);
    #pragma unroll
    for (int k=0;k<6;k++){ int x=u+64*k; float2 v=lrow[x]; xr[x*5]=v.x; xi[x*5]=v.y; }
    __syncthreads();
    fft384s<5,-1>(xr,xi,yr,yi,u,twr,twi);
    const float2* vrow = V + ((size_t)(c*ND+d)*NPIX + (size_t)y*NSZ);
    #pragma unroll
    for (int k=0;k<6;k++){
      int x=u+64*k;
      float acr=xr[x*5], aci=xi[x*5];
      float2 vv = vrow[x];
      float Vb = b ? vv.y : vv.x;
      float ic = 1.f/(aci + EPSV);
      acc[k]  += over[k] * (Vb * ic);
      over[k] *= (1.f - acr * ic);
    }
  }
  float* orow = out + ((size_t)(b*3 + c)*NPIX + (size_t)y*NSZ);
  #pragma unroll
  for (int k=0;k<6;k++) orow[u+64*k] = acc[k];
}

extern "C" void kernel_launch(void* const* d_in, const int* in_sizes, int n_in,
                              void* d_out, int out_size, void* d_ws, size_t ws_size,
                              hipStream_t stream){
  const float* img   = (const float*)d_in[0];   // (2,3,384,384) f32
  const float* depth = (const float*)d_in[1];   // (2,1,384,384) f32
  const void*  h1d   = d_in[2];                 // (1024,)
  const void*  amp   = d_in[3];                 // (3,16,1024)
  const void*  pph   = d_in[4];                 // (3,16,1024)
  const void*  Hm    = d_in[5];                 // (3,1024,194)
  const void*  rg    = d_in[6];                 // (3,194)
  const void*  rs    = d_in[7];                 // (3,192,192)
  float* out = (float*)d_out;
  (void)in_sizes; (void)n_in; (void)out_size;

  char* ws = (char*)d_ws;
  size_t off = 0;
  auto take = [&](size_t b)->char*{ char* p = ws + off; off += (b + 255) & ~(size_t)255; return p; };
  int*    flag  = (int*)   take(256);
  double* psf1d = (double*)take((size_t)48*NG*8);
  double* sums  = (double*)take((size_t)48*8);
  double* acs   = (double*)take((size_t)48*MS2*8);
  double* ass   = (double*)take((size_t)48*MS2*8);
  float*  q     = (float*) take((size_t)48*QPIX*4);       //  7.08 MB
  float*  Rr    = (float*) take((size_t)48*192*NSZ*4);    // 14.16 MB
  float*  Rc    = (float*) take((size_t)48*NPIX*4);       // 28.31 MB
  float2* V     = (float2*)take((size_t)48*NPIX*8);       // 56.62 MB
  float2* S     = (float2*)take((size_t)32*NPIX*8);       // 37.75 MB
  size_t needL16 = off + (size_t)16*NPIX*8;               // ~163.8 MB
  size_t needL96 = off + (size_t)96*NPIX*8;               // ~258.2 MB
  int tier = (ws_size >= needL96) ? 2 : (ws_size >= needL16) ? 1 : -1;
  if (tier < 0) return;   // clean absmax failure, not a fault
  float2* L = (float2*)take((size_t)(tier==2?96:16)*NPIX*8);

  k_detect<<<1, 1, 0, stream>>>(rg, flag);
  hipMemsetAsync(sums, 0, 48*8, stream);
  k_trig<<<48, 256, 0, stream>>>(h1d, amp, pph, flag, acs, ass);
  double2* part = (double2*)q;   // 1.19 MB, consumed by dotB before interp writes q
  k_dotA<<<48*8, 256, 0, stream>>>(acs, ass, Hm, flag, part);
  k_dotB<<<(48*NG+255)/256, 256, 0, stream>>>(part, psf1d);
  k_interp<<<48*144, 256, 0, stream>>>(psf1d, rg, rs, flag, q, sums);
  k_rows_fwd<<<48*24 + 48*96 + 32*96, 256, 0, stream>>>(q, sums, Rr, img, depth, V, S);
  k_cols_F<<<48*24, 512, 0, stream>>>(Rr, Rc);
  k_cols_S<<<32*48, 512, 0, stream>>>(S);
  k_fused <<<48*48, 512, 0, stream>>>(V, Rc);
  k_rowsinv<<<48*96, 256, 0, stream>>>(V);
  if (tier == 2){
    k_mulinv <<<6*16*48, 512, 0, stream>>>(S, Rc, L, 0);
    k_combine<<<6*96,   256, 0, stream>>>(L, V, out, 0);
  } else {
    for (int p=0; p<6; p++){
      k_mulinv <<<16*48, 512, 0, stream>>>(S, Rc, L, p);
      k_combine<<<96,   256, 0, stream>>>(L, V, out, p);
    }
  }
}